// Round 6
// baseline (5052.117 us; speedup 1.0000x reference)
//
#include <hip/hip_runtime.h>
#include <math.h>

#define BB 64
#define NN 512
#define DD 32
#define LD2 36           // sA leading dim (pad col 32 holds per-column tk)
#define LDG 32           // sG leading dim (broadcast/bank-r reads only)
#define JIT 1e-5f
#define TOLF 1e-4f
#define MAXIT 10

typedef float float2v __attribute__((ext_vector_type(2)));

// packed f32 math (VOP3P, gfx90a+): 2 elements per instruction
__device__ __forceinline__ float2v pk_fma(float2v a, float2v b, float2v c) {
    float2v d;
    asm("v_pk_fma_f32 %0, %1, %2, %3" : "=v"(d) : "v"(a), "v"(b), "v"(c));
    return d;
}
__device__ __forceinline__ float2v pk_mul(float2v a, float2v b) {
    float2v d;
    asm("v_pk_mul_f32 %0, %1, %2" : "=v"(d) : "v"(a), "v"(b));
    return d;
}

// lane-pull via LDS permute unit; addr = src_lane<<2 (epilogue reductions only)
__device__ __forceinline__ float bpf(int addr, float v) {
    return __int_as_float(__builtin_amdgcn_ds_bpermute(addr, __float_as_int(v)));
}

// lane^16 via the LDS crossbar (per-32-group xor16): 1 DS op, no VALU
__device__ __forceinline__ float swz16(float x) {
    return __int_as_float(__builtin_amdgcn_ds_swizzle(__float_as_int(x), 0x401F));
}

// cross-half (lane ^ 32) sum/max via VALU permlane32_swap (epilogue reduce only)
__device__ __forceinline__ float xhsum(float x) {
    unsigned u = __float_as_uint(x);
    auto r = __builtin_amdgcn_permlane32_swap(u, u, false, false);
    return __uint_as_float(r[0]) + __uint_as_float(r[1]);
}

__device__ __forceinline__ float xhmax(float x) {
    unsigned u = __float_as_uint(x);
    auto r = __builtin_amdgcn_permlane32_swap(u, u, false, false);
    return fmaxf(__uint_as_float(r[0]), __uint_as_float(r[1]));
}

__device__ __forceinline__ void wsync() {
    // wave-level LDS handoff (single-wave or per-wave-buffer use only)
    __asm__ volatile("s_waitcnt lgkmcnt(0)" ::: "memory");
}

// ---- VALU lane-exchange primitives (DPP + permlane) ----
template<int CTRL>
__device__ __forceinline__ float dppf(float x) {
    int i = __float_as_int(x);
    return __int_as_float(__builtin_amdgcn_update_dpp(i, i, CTRL, 0xF, 0xF, true));
}
// DPP ctrl: quad_perm[1,0,3,2]=0xB1 (xor1), [2,3,0,1]=0x4E (xor2),
// [3,2,1,0]=0x1B (xor3), row_ror:4=0x124, row_ror:8=0x128 (xor8),
// row_mirror=0x140 (xor15), row_half_mirror=0x141 (xor7)

// value of lane^16 (permlane16_swap pair-select; ds_swizzle fallback)
__device__ __forceinline__ float part16(float x, bool hi16) {
#if __has_builtin(__builtin_amdgcn_permlane16_swap)
    unsigned u = __float_as_uint(x);
    auto r = __builtin_amdgcn_permlane16_swap(u, u, false, false);
    return hi16 ? __uint_as_float(r[0]) : __uint_as_float(r[1]);
#else
    return swz16(x);
#endif
}

__device__ __forceinline__ float max16pair(float x) {
#if __has_builtin(__builtin_amdgcn_permlane16_swap)
    unsigned u = __float_as_uint(x);
    auto r = __builtin_amdgcn_permlane16_swap(u, u, false, false);
    return fmaxf(__uint_as_float(r[0]), __uint_as_float(r[1]));
#else
    return fmaxf(x, swz16(x));
#endif
}

// value of lane^LOW for LOW in 0..15, composed from DPP XOR{1,2,3,7,8,15}
template<int LOW>
__device__ __forceinline__ float xorlane_lo(float x) {
    float v = x;
    if constexpr (LOW == 1)  v = dppf<0xB1>(v);
    else if constexpr (LOW == 2)  v = dppf<0x4E>(v);
    else if constexpr (LOW == 3)  v = dppf<0x1B>(v);
    else if constexpr (LOW == 4)  { v = dppf<0x141>(v); v = dppf<0x1B>(v); }  // 7^3
    else if constexpr (LOW == 5)  { v = dppf<0x141>(v); v = dppf<0x4E>(v); }  // 7^2
    else if constexpr (LOW == 6)  { v = dppf<0x141>(v); v = dppf<0xB1>(v); }  // 7^1
    else if constexpr (LOW == 7)  v = dppf<0x141>(v);
    else if constexpr (LOW == 8)  v = dppf<0x128>(v);
    else if constexpr (LOW == 9)  { v = dppf<0x128>(v); v = dppf<0xB1>(v); }
    else if constexpr (LOW == 10) { v = dppf<0x128>(v); v = dppf<0x4E>(v); }
    else if constexpr (LOW == 11) { v = dppf<0x128>(v); v = dppf<0x1B>(v); }
    else if constexpr (LOW == 12) { v = dppf<0x140>(v); v = dppf<0x1B>(v); }  // 15^3
    else if constexpr (LOW == 13) { v = dppf<0x140>(v); v = dppf<0x4E>(v); }  // 15^2
    else if constexpr (LOW == 14) { v = dppf<0x140>(v); v = dppf<0xB1>(v); }  // 15^1
    else if constexpr (LOW == 15) v = dppf<0x140>(v);
    return v;
}

// full-wave max reduction, VALU-only (+16-swap), no DS
__device__ __forceinline__ float redmax32(float x) {
    x = fmaxf(x, dppf<0xB1>(x));    // xor1
    x = fmaxf(x, dppf<0x4E>(x));    // xor2
    x = fmaxf(x, dppf<0x124>(x));   // ror4: covers remaining quads
    x = fmaxf(x, dppf<0x128>(x));   // ror8
    x = max16pair(x);               // rows of 16 -> 32
    return xhmax(x);                // -> 64
}

// ---------------- one-sided (Hestenes) Jacobi, full-column-per-lane, packed ----------------
// Lane holds a FULL 32-elem column as float2v A[16]; lanes 0-31 = matrix A's
// columns, lanes 32-63 = matrix B's -> one rotation serves TWO matrices.
// Dots/updates use v_pk_fma_f32 (2 elems/instr); exchange is per-32-bit DPP.
template<int M>
__device__ __forceinline__ void rot32(float2v A[16], int c, bool hi16, float& maxrel) {
    constexpr int LOW = M & 15;
    float2v PA[16];
#pragma unroll
    for (int i = 0; i < 16; ++i) {
        float tx = xorlane_lo<LOW>(A[i].x);
        float ty = xorlane_lo<LOW>(A[i].y);
        if constexpr (M >= 16) {
            tx = (i < 8) ? swz16(tx) : part16(tx, hi16);
            ty = (i < 8) ? swz16(ty) : part16(ty, hi16);
        }
        PA[i].x = tx; PA[i].y = ty;
    }
    float2v GS = {0.f, 0.f}, GC = {0.f, 0.f};
#pragma unroll
    for (int i = 0; i < 16; ++i) {
        GS = pk_fma(A[i], A[i], GS);
        GC = pk_fma(A[i], PA[i], GC);
    }
    float gs = GS.x + GS.y;
    float gc = GC.x + GC.y;
    float gp;
    if constexpr (M < 16) gp = xorlane_lo<LOW>(gs);
    else                  gp = swz16(xorlane_lo<LOW>(gs));
    bool isP = c < (c ^ M);
    float gpp = isP ? gs : gp;
    float gqq = isP ? gp : gs;
    float rel = gc * gc * __builtin_amdgcn_rcpf(gpp * gqq);
    maxrel = fmaxf(maxrel, rel);
    float tau = (gqq - gpp) * (0.5f * __builtin_amdgcn_rcpf(gc));
    float den = fabsf(tau) + __builtin_amdgcn_sqrtf(fmaf(tau, tau, 1.f));
    float tt  = copysignf(__builtin_amdgcn_rcpf(den), tau);
    tt = (rel > 1e-24f) ? tt : 0.f;
    float cs  = __builtin_amdgcn_rsqf(fmaf(tt, tt, 1.f));
    float sn  = tt * cs;
    float sg = isP ? -sn : sn;
    float2v CS2 = {cs, cs}, SG2 = {sg, sg};
#pragma unroll
    for (int i = 0; i < 16; ++i)
        A[i] = pk_fma(SG2, PA[i], pk_mul(CS2, A[i]));
}

__device__ __forceinline__ void jac_pair(float2v A[16], int c, bool hi16,
                                         int maxsweep, float thr) {
#pragma unroll 1
    for (int sweep = 0; sweep < maxsweep; ++sweep) {
        float maxrel = 0.f;
        rot32<1>(A, c, hi16, maxrel);  rot32<2>(A, c, hi16, maxrel);
        rot32<3>(A, c, hi16, maxrel);  rot32<4>(A, c, hi16, maxrel);
        rot32<5>(A, c, hi16, maxrel);  rot32<6>(A, c, hi16, maxrel);
        rot32<7>(A, c, hi16, maxrel);  rot32<8>(A, c, hi16, maxrel);
        rot32<9>(A, c, hi16, maxrel);  rot32<10>(A, c, hi16, maxrel);
        rot32<11>(A, c, hi16, maxrel); rot32<12>(A, c, hi16, maxrel);
        rot32<13>(A, c, hi16, maxrel); rot32<14>(A, c, hi16, maxrel);
        rot32<15>(A, c, hi16, maxrel); rot32<16>(A, c, hi16, maxrel);
        rot32<17>(A, c, hi16, maxrel); rot32<18>(A, c, hi16, maxrel);
        rot32<19>(A, c, hi16, maxrel); rot32<20>(A, c, hi16, maxrel);
        rot32<21>(A, c, hi16, maxrel); rot32<22>(A, c, hi16, maxrel);
        rot32<23>(A, c, hi16, maxrel); rot32<24>(A, c, hi16, maxrel);
        rot32<25>(A, c, hi16, maxrel); rot32<26>(A, c, hi16, maxrel);
        rot32<27>(A, c, hi16, maxrel); rot32<28>(A, c, hi16, maxrel);
        rot32<29>(A, c, hi16, maxrel); rot32<30>(A, c, hi16, maxrel);
        rot32<31>(A, c, hi16, maxrel);
        maxrel = redmax32(maxrel);   // ties the pair: waits for the slower matrix
        if (maxrel < thr) break;
    }
}

// C = A * B (32x32, both stride LD2). Wave-synchronous, in-place safe (single wave).
__device__ __forceinline__ void mm32w(const float* A, const float* B, float* C, int lane) {
    int r = lane >> 1, cb = (lane & 1) << 4;
    float acc[16];
#pragma unroll
    for (int j = 0; j < 16; ++j) acc[j] = 0.0f;
    for (int k = 0; k < DD; ++k) {
        float a = A[r * LD2 + k];
        const float4* Br = (const float4*)(B + k * LD2 + cb);
        float4 b0 = Br[0], b1 = Br[1], b2 = Br[2], b3 = Br[3];
        acc[0]  = fmaf(a, b0.x, acc[0]);  acc[1]  = fmaf(a, b0.y, acc[1]);
        acc[2]  = fmaf(a, b0.z, acc[2]);  acc[3]  = fmaf(a, b0.w, acc[3]);
        acc[4]  = fmaf(a, b1.x, acc[4]);  acc[5]  = fmaf(a, b1.y, acc[5]);
        acc[6]  = fmaf(a, b1.z, acc[6]);  acc[7]  = fmaf(a, b1.w, acc[7]);
        acc[8]  = fmaf(a, b2.x, acc[8]);  acc[9]  = fmaf(a, b2.y, acc[9]);
        acc[10] = fmaf(a, b2.z, acc[10]); acc[11] = fmaf(a, b2.w, acc[11]);
        acc[12] = fmaf(a, b3.x, acc[12]); acc[13] = fmaf(a, b3.y, acc[13]);
        acc[14] = fmaf(a, b3.z, acc[14]); acc[15] = fmaf(a, b3.w, acc[15]);
    }
    wsync();
    float4* Cr = (float4*)(C + r * LD2 + cb);
    Cr[0] = make_float4(acc[0],  acc[1],  acc[2],  acc[3]);
    Cr[1] = make_float4(acc[4],  acc[5],  acc[6],  acc[7]);
    Cr[2] = make_float4(acc[8],  acc[9],  acc[10], acc[11]);
    Cr[3] = make_float4(acc[12], acc[13], acc[14], acc[15]);
    wsync();
}

// ---------------- setup ----------------

__global__ __launch_bounds__(256) void k0_zero(float* __restrict__ G, int* __restrict__ done,
                                               float* __restrict__ norm_acc, int* __restrict__ cnt_all,
                                               int* __restrict__ cnt_b) {
    float4* Gb = (float4*)(G + blockIdx.x * 1024);
    Gb[threadIdx.x] = make_float4(0.f, 0.f, 0.f, 0.f);
    if (blockIdx.x == 0) {
        if (threadIdx.x == 0) { *done = 0; *norm_acc = 0.f; *cnt_all = 0; }
        if (threadIdx.x < BB) cnt_b[threadIdx.x] = 0;
    }
}

__global__ __launch_bounds__(256) void k0_mean(const float* __restrict__ X, float* __restrict__ G) {
    int blk = blockIdx.x;
    int b = blk >> 3, chunk = blk & 7;
    int t = threadIdx.x;
    const float4* Xb = (const float4*)(X + ((size_t)(b * NN + chunk * 64)) * 1024);
    float4 acc = make_float4(0.f, 0.f, 0.f, 0.f);
    for (int n = 0; n < 64; ++n) {
        float4 v = Xb[n * 256 + t];
        acc.x += v.x; acc.y += v.y; acc.z += v.z; acc.w += v.w;
    }
    const float inv = 1.0f / NN;
    float* Gb = G + b * 1024 + t * 4;
    atomicAdd(Gb + 0, acc.x * inv);
    atomicAdd(Gb + 1, acc.y * inv);
    atomicAdd(Gb + 2, acc.z * inv);
    atomicAdd(Gb + 3, acc.w * inv);
}

// ---------------- k1: initial eigh(G0) -> Gs, Gis; seed Vg (once) ----------------

__global__ __launch_bounds__(64) void k1_init(const float* __restrict__ G,
                                              float* __restrict__ Gs, float* __restrict__ Gis,
                                              float* __restrict__ Vg) {
    int b = blockIdx.x, lane = threadIdx.x;
    int c = lane & 31;
    bool hi16 = (lane & 16) != 0;
    int r = lane >> 1, cb = (lane & 1) << 4;
    __shared__ __align__(16) float sW[DD * LD2];
    __shared__ float sc1[DD], sc2[DD];

    float2v A[16];
    {
        // G symmetric: row c == column c; both halves duplicate the matrix
        const float4* Gc = (const float4*)(G + b * 1024 + c * 32);
#pragma unroll
        for (int j4 = 0; j4 < 8; ++j4) {
            float4 q = Gc[j4];
            int e = 4 * j4;
            A[2*j4].x   = q.x + ((e + 0) == c ? JIT : 0.f);
            A[2*j4].y   = q.y + ((e + 1) == c ? JIT : 0.f);
            A[2*j4+1].x = q.z + ((e + 2) == c ? JIT : 0.f);
            A[2*j4+1].y = q.w + ((e + 3) == c ? JIT : 0.f);
        }
    }
    jac_pair(A, c, hi16, 10, 1e-12f);
    float2v GSv = {0.f, 0.f};
#pragma unroll
    for (int j = 0; j < 16; ++j) GSv = pk_fma(A[j], A[j], GSv);
    float gs2 = GSv.x + GSv.y;
    float l  = __builtin_amdgcn_sqrtf(gs2);
    float lc = fmaxf(l, JIT);
    float ig = __builtin_amdgcn_rcpf(gs2);
    float c1 = __builtin_amdgcn_sqrtf(lc) * ig;   // sqrt(clip(lam)) / lam^2
    float c2 = __builtin_amdgcn_rsqf(lc) * ig;    // 1/sqrt(clip(lam)) / lam^2
    if (Vg && lane < 32) {   // seed warm-start basis for the fused epilogue
        float inl = __builtin_amdgcn_rsqf(gs2);
        float4* Vp = (float4*)(Vg + b * 1024 + c * 32);
#pragma unroll
        for (int j4 = 0; j4 < 8; ++j4)
            Vp[j4] = make_float4(A[2*j4].x*inl, A[2*j4].y*inl, A[2*j4+1].x*inl, A[2*j4+1].y*inl);
    }
    if (lane < 32) {
        float4* wp = (float4*)&sW[c * LD2];   // sW[c][i] = W[i][c]  (W^T rows)
#pragma unroll
        for (int j4 = 0; j4 < 8; ++j4)
            wp[j4] = make_float4(A[2*j4].x, A[2*j4].y, A[2*j4+1].x, A[2*j4+1].y);
        sc1[c] = c1; sc2[c] = c2;
    }
    wsync();
    float a1[16], a2[16];
#pragma unroll
    for (int j = 0; j < 16; ++j) { a1[j] = 0.f; a2[j] = 0.f; }
    for (int k = 0; k < DD; ++k) {
        float wr = sW[k * LD2 + r];
        float t1 = wr * sc1[k], t2 = wr * sc2[k];
        const float4* Wc = (const float4*)&sW[k * LD2 + cb];
        float4 w0 = Wc[0], w1 = Wc[1], w2 = Wc[2], w3 = Wc[3];
        a1[0]+=t1*w0.x; a2[0]+=t2*w0.x;  a1[1]+=t1*w0.y; a2[1]+=t2*w0.y;
        a1[2]+=t1*w0.z; a2[2]+=t2*w0.z;  a1[3]+=t1*w0.w; a2[3]+=t2*w0.w;
        a1[4]+=t1*w1.x; a2[4]+=t2*w1.x;  a1[5]+=t1*w1.y; a2[5]+=t2*w1.y;
        a1[6]+=t1*w1.z; a2[6]+=t2*w1.z;  a1[7]+=t1*w1.w; a2[7]+=t2*w1.w;
        a1[8]+=t1*w2.x; a2[8]+=t2*w2.x;  a1[9]+=t1*w2.y; a2[9]+=t2*w2.y;
        a1[10]+=t1*w2.z; a2[10]+=t2*w2.z; a1[11]+=t1*w2.w; a2[11]+=t2*w2.w;
        a1[12]+=t1*w3.x; a2[12]+=t2*w3.x; a1[13]+=t1*w3.y; a2[13]+=t2*w3.y;
        a1[14]+=t1*w3.z; a2[14]+=t2*w3.z; a1[15]+=t1*w3.w; a2[15]+=t2*w3.w;
    }
    float4* Gsb  = (float4*)(Gs  + b * 1024 + lane * 16);
    float4* Gisb = (float4*)(Gis + b * 1024 + lane * 16);
#pragma unroll
    for (int j4 = 0; j4 < 4; ++j4) {
        Gsb[j4]  = make_float4(a1[4*j4], a1[4*j4+1], a1[4*j4+2], a1[4*j4+3]);
        Gisb[j4] = make_float4(a2[4*j4], a2[4*j4+1], a2[4*j4+2], a2[4*j4+3]);
    }
}

// ---------------- k2: hot kernel + fused per-b epilogue ----------------
// 1024 blocks x 8 waves; wave handles 4 matrices as 2 pairs. waves_per_eu(2,4)
// caps the allocator's occupancy target -> VGPR budget 128+, no spill of the
// 64-reg Jacobi state (R5's VGPR=64 choice forced spills/remat).

__global__ __launch_bounds__(512) __attribute__((amdgpu_waves_per_eu(2, 4)))
void k2_log_acc(const float* __restrict__ X,
                float* G, float* Gs, float* Gis,
                float* __restrict__ Part,
                int* __restrict__ done,
                float* __restrict__ Vbuf,
                float* __restrict__ Vg,
                float* __restrict__ norm_acc,
                int* __restrict__ cnt_all,
                int* __restrict__ cnt_b,
                int it) {
    if (*done) return;
    int b = blockIdx.x >> 4, grp = blockIdx.x & 15;
    int wv = threadIdx.x >> 6, lane = threadIdx.x & 63;
    int c = lane & 31, h = lane >> 5;
    bool hi16 = (lane & 16) != 0;
    int aself = lane << 2;

    __shared__ __align__(16) float sG[DD * LDG];           // 4096 B
    __shared__ __align__(16) float sAall[8][DD * LD2];     // 36864 B
    float* sA = sAall[wv];

    if (threadIdx.x < 256)
        ((float4*)sG)[threadIdx.x] = ((const float4*)(Gis + b * 1024))[threadIdx.x];
    __syncthreads();

    int r = lane >> 1, cb = (lane & 1) << 4;
    float dacc[16];
#pragma unroll
    for (int j = 0; j < 16; ++j) dacc[j] = 0.f;

#pragma unroll 1
    for (int pp = 0; pp < 2; ++pp) {
        int nb = grp * 32 + wv * 4 + pp * 2;
        float2v A[16];
#pragma unroll 1
        for (int half = 0; half < 2; ++half) {
            int n = nb + half;
            // ---- stage X[b,n] -> sA ----
            {
                const float4* Xv = (const float4*)(X + ((size_t)(b * NN + n)) * 1024);
                float4 v0 = Xv[lane * 4 + 0], v1 = Xv[lane * 4 + 1];
                float4 v2 = Xv[lane * 4 + 2], v3 = Xv[lane * 4 + 3];
                wsync();   // all prior readers of sA done
                int e = lane * 16;
                float* d0 = &sA[(e >> 5) * LD2 + (e & 31)];
                *((float4*)d0)        = v0;
                *((float4*)(d0 + 4))  = v1;
                *((float4*)(d0 + 8))  = v2;
                *((float4*)(d0 + 12)) = v3;
                wsync();
            }
            // ---- T = Gis * X (A-operand transposed read from sG: conflict-free) ----
            {
                float acc[16];
#pragma unroll
                for (int j = 0; j < 16; ++j) acc[j] = 0.f;
                for (int k = 0; k < DD; ++k) {
                    float av = sG[k * LDG + r];
                    const float4* Br = (const float4*)(sA + k * LD2 + cb);
                    float4 b0 = Br[0], b1 = Br[1], b2 = Br[2], b3 = Br[3];
                    acc[0]  = fmaf(av, b0.x, acc[0]);  acc[1]  = fmaf(av, b0.y, acc[1]);
                    acc[2]  = fmaf(av, b0.z, acc[2]);  acc[3]  = fmaf(av, b0.w, acc[3]);
                    acc[4]  = fmaf(av, b1.x, acc[4]);  acc[5]  = fmaf(av, b1.y, acc[5]);
                    acc[6]  = fmaf(av, b1.z, acc[6]);  acc[7]  = fmaf(av, b1.w, acc[7]);
                    acc[8]  = fmaf(av, b2.x, acc[8]);  acc[9]  = fmaf(av, b2.y, acc[9]);
                    acc[10] = fmaf(av, b2.z, acc[10]); acc[11] = fmaf(av, b2.w, acc[11]);
                    acc[12] = fmaf(av, b3.x, acc[12]); acc[13] = fmaf(av, b3.y, acc[13]);
                    acc[14] = fmaf(av, b3.z, acc[14]); acc[15] = fmaf(av, b3.w, acc[15]);
                }
                wsync();
                float4* Cr = (float4*)(sA + r * LD2 + cb);
                Cr[0] = make_float4(acc[0],  acc[1],  acc[2],  acc[3]);
                Cr[1] = make_float4(acc[4],  acc[5],  acc[6],  acc[7]);
                Cr[2] = make_float4(acc[8],  acc[9],  acc[10], acc[11]);
                Cr[3] = make_float4(acc[12], acc[13], acc[14], acc[15]);
                wsync();
            }
            // ---- A = T * Gis ----
            {
                float acc[16];
#pragma unroll
                for (int j = 0; j < 16; ++j) acc[j] = 0.f;
                for (int k = 0; k < DD; ++k) {
                    float av = sA[r * LD2 + k];
                    const float4* Br = (const float4*)(sG + k * LDG + cb);
                    float4 b0 = Br[0], b1 = Br[1], b2 = Br[2], b3 = Br[3];
                    acc[0]  = fmaf(av, b0.x, acc[0]);  acc[1]  = fmaf(av, b0.y, acc[1]);
                    acc[2]  = fmaf(av, b0.z, acc[2]);  acc[3]  = fmaf(av, b0.w, acc[3]);
                    acc[4]  = fmaf(av, b1.x, acc[4]);  acc[5]  = fmaf(av, b1.y, acc[5]);
                    acc[6]  = fmaf(av, b1.z, acc[6]);  acc[7]  = fmaf(av, b1.w, acc[7]);
                    acc[8]  = fmaf(av, b2.x, acc[8]);  acc[9]  = fmaf(av, b2.y, acc[9]);
                    acc[10] = fmaf(av, b2.z, acc[10]); acc[11] = fmaf(av, b2.w, acc[11]);
                    acc[12] = fmaf(av, b3.x, acc[12]); acc[13] = fmaf(av, b3.y, acc[13]);
                    acc[14] = fmaf(av, b3.z, acc[14]); acc[15] = fmaf(av, b3.w, acc[15]);
                }
                wsync();
                float4* Cr = (float4*)(sA + r * LD2 + cb);
                Cr[0] = make_float4(acc[0],  acc[1],  acc[2],  acc[3]);
                Cr[1] = make_float4(acc[4],  acc[5],  acc[6],  acc[7]);
                Cr[2] = make_float4(acc[8],  acc[9],  acc[10], acc[11]);
                Cr[3] = make_float4(acc[12], acc[13], acc[14], acc[15]);
                wsync();
            }
            // ---- my half loads its full columns into registers (packed pairs) ----
            if (h == half) {
                if (it == 0) {
                    float tr[32];   // row c of A
                    const float4* rp = (const float4*)&sA[c * LD2];
#pragma unroll
                    for (int j4 = 0; j4 < 8; ++j4) {
                        float4 q = rp[j4];
                        tr[4*j4]=q.x; tr[4*j4+1]=q.y; tr[4*j4+2]=q.z; tr[4*j4+3]=q.w;
                    }
#pragma unroll
                    for (int j = 0; j < 16; ++j) {
                        int i0 = 2*j, i1 = 2*j + 1;
                        float v0 = 0.5f * (sA[i0 * LD2 + c] + tr[i0]);
                        float v1 = 0.5f * (sA[i1 * LD2 + c] + tr[i1]);
                        A[j].x = (i0 == c) ? (tr[i0] + JIT) : v0;
                        A[j].y = (i1 == c) ? (tr[i1] + JIT) : v1;
                    }
                } else {
                    // w_c = (A + JIT I) * vhat_prev_c  (packed dot)
                    float2v V2[16];
                    const float4* Vp = (const float4*)(Vbuf + ((size_t)(b * NN + n)) * 1024 + c * 32);
#pragma unroll
                    for (int j4 = 0; j4 < 8; ++j4) {
                        float4 t = Vp[j4];
                        V2[2*j4].x   = t.x; V2[2*j4].y   = t.y;
                        V2[2*j4+1].x = t.z; V2[2*j4+1].y = t.w;
                    }
#pragma unroll
                    for (int j = 0; j < 16; ++j) {
                        const float4* Ar0 = (const float4*)&sA[(2*j) * LD2];
                        const float4* Ar1 = (const float4*)&sA[(2*j+1) * LD2];
                        float2v acc0 = {0.f, 0.f}, acc1 = {0.f, 0.f};
#pragma unroll
                        for (int j4 = 0; j4 < 8; ++j4) {
                            float4 q0 = Ar0[j4], q1 = Ar1[j4];
                            float2v q0a = {q0.x, q0.y}, q0b = {q0.z, q0.w};
                            float2v q1a = {q1.x, q1.y}, q1b = {q1.z, q1.w};
                            acc0 = pk_fma(q0a, V2[2*j4],   acc0);
                            acc0 = pk_fma(q0b, V2[2*j4+1], acc0);
                            acc1 = pk_fma(q1a, V2[2*j4],   acc1);
                            acc1 = pk_fma(q1b, V2[2*j4+1], acc1);
                        }
                        A[j].x = fmaf(JIT, V2[j].x, acc0.x + acc0.y);
                        A[j].y = fmaf(JIT, V2[j].y, acc1.x + acc1.y);
                    }
                }
            }
        }

        jac_pair(A, c, hi16, 8, 1e-8f);

        // ---- eigen extraction (lane-local, packed) + V store ----
        float2v GSv = {0.f, 0.f};
#pragma unroll
        for (int j = 0; j < 16; ++j) GSv = pk_fma(A[j], A[j], GSv);
        float gs2 = GSv.x + GSv.y;
        float gs2c = fmaxf(gs2, JIT * JIT);
        float tk = 0.5f * logf(gs2c) * __builtin_amdgcn_rcpf(gs2);
        if (Vbuf) {   // store normalized eigenvectors for next iteration's warm start
            int n = nb + h;
            float inl = __builtin_amdgcn_rsqf(gs2);
            float4* Vp = (float4*)(Vbuf + ((size_t)(b * NN + n)) * 1024 + c * 32);
#pragma unroll
            for (int j4 = 0; j4 < 8; ++j4)
                Vp[j4] = make_float4(A[2*j4].x*inl, A[2*j4].y*inl, A[2*j4+1].x*inl, A[2*j4+1].y*inl);
        }
        // ---- per half: writeback W^T + tk, rebuild into dacc ----
#pragma unroll 1
        for (int half = 0; half < 2; ++half) {
            wsync();   // prior readers of sA done
            if (h == half) {
                float4* wp = (float4*)&sA[c * LD2];   // sA[c][i] = W[i][c]
#pragma unroll
                for (int j4 = 0; j4 < 8; ++j4)
                    wp[j4] = make_float4(A[2*j4].x, A[2*j4].y, A[2*j4+1].x, A[2*j4+1].y);
                sA[c * LD2 + 32] = tk;
            }
            wsync();
            for (int k = 0; k < DD; ++k) {
                float t1 = sA[k * LD2 + r] * sA[k * LD2 + 32];
                const float4* Wr = (const float4*)&sA[k * LD2 + cb];
                float4 w0 = Wr[0], w1 = Wr[1], w2 = Wr[2], w3 = Wr[3];
                dacc[0]  = fmaf(t1, w0.x, dacc[0]);  dacc[1]  = fmaf(t1, w0.y, dacc[1]);
                dacc[2]  = fmaf(t1, w0.z, dacc[2]);  dacc[3]  = fmaf(t1, w0.w, dacc[3]);
                dacc[4]  = fmaf(t1, w1.x, dacc[4]);  dacc[5]  = fmaf(t1, w1.y, dacc[5]);
                dacc[6]  = fmaf(t1, w1.z, dacc[6]);  dacc[7]  = fmaf(t1, w1.w, dacc[7]);
                dacc[8]  = fmaf(t1, w2.x, dacc[8]);  dacc[9]  = fmaf(t1, w2.y, dacc[9]);
                dacc[10] = fmaf(t1, w2.z, dacc[10]); dacc[11] = fmaf(t1, w2.w, dacc[11]);
                dacc[12] = fmaf(t1, w3.x, dacc[12]); dacc[13] = fmaf(t1, w3.y, dacc[13]);
                dacc[14] = fmaf(t1, w3.z, dacc[14]); dacc[15] = fmaf(t1, w3.w, dacc[15]);
            }
        }
    }
    wsync();

    // ---- block reduction -> Part ----
    {
        float4* fp = (float4*)&sA[lane * 16];
        fp[0] = make_float4(dacc[0],  dacc[1],  dacc[2],  dacc[3]);
        fp[1] = make_float4(dacc[4],  dacc[5],  dacc[6],  dacc[7]);
        fp[2] = make_float4(dacc[8],  dacc[9],  dacc[10], dacc[11]);
        fp[3] = make_float4(dacc[12], dacc[13], dacc[14], dacc[15]);
    }
    __syncthreads();
    if (threadIdx.x < 256) {
        int t = threadIdx.x;
        float4 s0 = ((float4*)sAall[0])[t];
        float4 s1 = ((float4*)sAall[1])[t];
        float4 s2 = ((float4*)sAall[2])[t];
        float4 s3 = ((float4*)sAall[3])[t];
        float4 s4 = ((float4*)sAall[4])[t];
        float4 s5 = ((float4*)sAall[5])[t];
        float4 s6 = ((float4*)sAall[6])[t];
        float4 s7 = ((float4*)sAall[7])[t];
        float4 s;
        s.x = ((s0.x + s1.x) + (s2.x + s3.x)) + ((s4.x + s5.x) + (s6.x + s7.x));
        s.y = ((s0.y + s1.y) + (s2.y + s3.y)) + ((s4.y + s5.y) + (s6.y + s7.y));
        s.z = ((s0.z + s1.z) + (s2.z + s3.z)) + ((s4.z + s5.z) + (s6.z + s7.z));
        s.w = ((s0.w + s1.w) + (s2.w + s3.w)) + ((s4.w + s5.w) + (s6.w + s7.w));
        ((float4*)(Part + (size_t)blockIdx.x * 1024))[t] = s;
    }

    // ---- elect last-finishing block of this b ----
    int* winp = (int*)sG;   // sG dead now; reuse 4 bytes
    if (threadIdx.x == 0) *winp = 0;
    __syncthreads();        // Part stores complete (intra-block) + winp init
    if (threadIdx.x == 0) {
        __threadfence();    // release: our Part visible before count
        int ret = atomicAdd(&cnt_b[b], 1);
        if (ret == 15) { *winp = 1; cnt_b[b] = 0; }
    }
    __syncthreads();
    if (*winp == 0) return;
    if (threadIdx.x >= 64) return;
    __threadfence();        // acquire: other blocks' Part now visible

    // ==== fused epilogue, wave 0 only ====
    {
        float* s0 = sAall[0];
        float* s1 = sAall[1];
        float* s2 = sAall[2];
        float* scof = sAall[3];   // [0..31] G, [32..63] Gs, [64..95] Gis coefficients

        // Delta = sum of 16 partials / NN
        float d[16];
#pragma unroll
        for (int j = 0; j < 16; ++j) d[j] = 0.f;
#pragma unroll 1
        for (int g = 0; g < 16; ++g) {
            const float4* P = (const float4*)(Part + (size_t)(b * 16 + g) * 1024 + lane * 16);
            float4 p0 = P[0], p1 = P[1], p2 = P[2], p3 = P[3];
            d[0]+=p0.x; d[1]+=p0.y; d[2]+=p0.z; d[3]+=p0.w;
            d[4]+=p1.x; d[5]+=p1.y; d[6]+=p1.z; d[7]+=p1.w;
            d[8]+=p2.x; d[9]+=p2.y; d[10]+=p2.z; d[11]+=p2.w;
            d[12]+=p3.x; d[13]+=p3.y; d[14]+=p3.z; d[15]+=p3.w;
        }
        const float inv = 1.0f / NN;
        float sumsq = 0.f;
#pragma unroll
        for (int j = 0; j < 16; ++j) { d[j] *= inv; sumsq = fmaf(d[j], d[j], sumsq); }
#pragma unroll
        for (int sh = 1; sh <= 16; sh <<= 1) sumsq += bpf(aself ^ (sh << 2), sumsq);
        sumsq = xhsum(sumsq);
        if (lane == 0) atomicAdd(norm_acc, sqrtf(sumsq));

        wsync();   // all waves' reduction reads of sAall are done (post-barrier); safe to overwrite
        // Delta -> s0
        {
            float4* dp = (float4*)&s0[r * LD2 + cb];
            dp[0] = make_float4(d[0],  d[1],  d[2],  d[3]);
            dp[1] = make_float4(d[4],  d[5],  d[6],  d[7]);
            dp[2] = make_float4(d[8],  d[9],  d[10], d[11]);
            dp[3] = make_float4(d[12], d[13], d[14], d[15]);
        }
        wsync();

        // expm_taylor order 5
        float outr[16];
#pragma unroll
        for (int j = 0; j < 16; ++j)
            outr[j] = ((cb + j) == r ? 1.0f : 0.0f) + d[j];
        float fac = 1.0f;
#pragma unroll 1
        for (int i = 2; i <= 5; ++i) {
            fac *= (float)i;
            float acc[16];
#pragma unroll
            for (int j = 0; j < 16; ++j) acc[j] = 0.f;
            const float* Xp = (i == 2) ? s0 : s1;
            for (int k = 0; k < DD; ++k) {
                float av = Xp[r * LD2 + k];
                const float4* Br = (const float4*)&s0[k * LD2 + cb];
                float4 b0 = Br[0], b1 = Br[1], b2 = Br[2], b3 = Br[3];
                acc[0]+=av*b0.x; acc[1]+=av*b0.y; acc[2]+=av*b0.z; acc[3]+=av*b0.w;
                acc[4]+=av*b1.x; acc[5]+=av*b1.y; acc[6]+=av*b1.z; acc[7]+=av*b1.w;
                acc[8]+=av*b2.x; acc[9]+=av*b2.y; acc[10]+=av*b2.z; acc[11]+=av*b2.w;
                acc[12]+=av*b3.x; acc[13]+=av*b3.y; acc[14]+=av*b3.z; acc[15]+=av*b3.w;
            }
            float invf = 1.0f / fac;
#pragma unroll
            for (int j = 0; j < 16; ++j) outr[j] = fmaf(acc[j], invf, outr[j]);
            wsync();
            float4* dp = (float4*)&s1[r * LD2 + cb];
            dp[0] = make_float4(acc[0],  acc[1],  acc[2],  acc[3]);
            dp[1] = make_float4(acc[4],  acc[5],  acc[6],  acc[7]);
            dp[2] = make_float4(acc[8],  acc[9],  acc[10], acc[11]);
            dp[3] = make_float4(acc[12], acc[13], acc[14], acc[15]);
            wsync();
        }
        // E -> s0; Gs_old -> s1
        {
            float4* dp = (float4*)&s0[r * LD2 + cb];
            dp[0] = make_float4(outr[0],  outr[1],  outr[2],  outr[3]);
            dp[1] = make_float4(outr[4],  outr[5],  outr[6],  outr[7]);
            dp[2] = make_float4(outr[8],  outr[9],  outr[10], outr[11]);
            dp[3] = make_float4(outr[12], outr[13], outr[14], outr[15]);
            const float4* Gsb = (const float4*)(Gs + b * 1024);
#pragma unroll
            for (int j4 = 0; j4 < 4; ++j4) {
                float4 v = Gsb[lane * 4 + j4];
                int e = lane * 16 + j4 * 4;
                *((float4*)&s1[(e >> 5) * LD2 + (e & 31)]) = v;
            }
        }
        wsync();
        mm32w(s1, s0, s2, lane);   // T = Gs * E
        mm32w(s2, s1, s0, lane);   // M = T * Gs

        // enforce_spd eigh (full-column packed layout; both halves duplicate the matrix)
        float2v AA[16];
        if (Vg == nullptr) {
            float tr[32];
            const float4* rp = (const float4*)&s0[c * LD2];
#pragma unroll
            for (int j4 = 0; j4 < 8; ++j4) {
                float4 q = rp[j4];
                tr[4*j4]=q.x; tr[4*j4+1]=q.y; tr[4*j4+2]=q.z; tr[4*j4+3]=q.w;
            }
#pragma unroll
            for (int j = 0; j < 16; ++j) {
                int i0 = 2*j, i1 = 2*j + 1;
                float v0 = 0.5f * (s0[i0 * LD2 + c] + tr[i0]);
                float v1 = 0.5f * (s0[i1 * LD2 + c] + tr[i1]);
                AA[j].x = (i0 == c) ? (tr[i0] + JIT) : v0;
                AA[j].y = (i1 == c) ? (tr[i1] + JIT) : v1;
            }
        } else {
            float2v V2[16];
            const float4* Vp = (const float4*)(Vg + b * 1024 + c * 32);
#pragma unroll
            for (int j4 = 0; j4 < 8; ++j4) {
                float4 t = Vp[j4];
                V2[2*j4].x   = t.x; V2[2*j4].y   = t.y;
                V2[2*j4+1].x = t.z; V2[2*j4+1].y = t.w;
            }
#pragma unroll
            for (int j = 0; j < 16; ++j) {
                const float4* Mr0 = (const float4*)&s0[(2*j) * LD2];
                const float4* Mr1 = (const float4*)&s0[(2*j+1) * LD2];
                float2v acc0 = {0.f, 0.f}, acc1 = {0.f, 0.f};
#pragma unroll
                for (int j4 = 0; j4 < 8; ++j4) {
                    float4 q0 = Mr0[j4], q1 = Mr1[j4];
                    float2v q0a = {q0.x, q0.y}, q0b = {q0.z, q0.w};
                    float2v q1a = {q1.x, q1.y}, q1b = {q1.z, q1.w};
                    acc0 = pk_fma(q0a, V2[2*j4],   acc0);
                    acc0 = pk_fma(q0b, V2[2*j4+1], acc0);
                    acc1 = pk_fma(q1a, V2[2*j4],   acc1);
                    acc1 = pk_fma(q1b, V2[2*j4+1], acc1);
                }
                AA[j].x = fmaf(JIT, V2[j].x, acc0.x + acc0.y);
                AA[j].y = fmaf(JIT, V2[j].y, acc1.x + acc1.y);
            }
        }
        jac_pair(AA, c, hi16, 10, 1e-12f);
        float2v GSv = {0.f, 0.f};
#pragma unroll
        for (int j = 0; j < 16; ++j) GSv = pk_fma(AA[j], AA[j], GSv);
        float gs2 = GSv.x + GSv.y;
        float l = __builtin_amdgcn_sqrtf(gs2);
        float clipl = fmaxf(l, JIT);
        float ig = __builtin_amdgcn_rcpf(gs2);
        float tg = clipl * ig;                      // G:   clip(lam)/lam^2
        float sh = clipl + JIT;                     // next eigh's vals (same eigvecs)
        float ts = __builtin_amdgcn_sqrtf(sh) * ig; // Gs:  sqrt(clip+JIT)/lam^2
        float ti = __builtin_amdgcn_rsqf(sh) * ig;  // Gis: rsqrt(clip+JIT)/lam^2
        if (Vg && lane < 32) {   // store normalized eigvecs for next iteration's warm start
            float inl = __builtin_amdgcn_rsqf(gs2);
            float4* Vp = (float4*)(Vg + b * 1024 + c * 32);
#pragma unroll
            for (int j4 = 0; j4 < 8; ++j4)
                Vp[j4] = make_float4(AA[2*j4].x*inl, AA[2*j4].y*inl, AA[2*j4+1].x*inl, AA[2*j4+1].y*inl);
        }
        wsync();
        // W -> s1 (W^T rows), coeffs -> scof
        if (lane < 32) {
            float4* wp = (float4*)&s1[c * LD2];
#pragma unroll
            for (int j4 = 0; j4 < 8; ++j4)
                wp[j4] = make_float4(AA[2*j4].x, AA[2*j4].y, AA[2*j4+1].x, AA[2*j4+1].y);
            scof[c] = tg; scof[32 + c] = ts; scof[64 + c] = ti;
        }
        wsync();
        // three low-register passes: G, Gs, Gis = W diag(coef) W^T
#pragma unroll 1
        for (int pass = 0; pass < 3; ++pass) {
            float g[16];
#pragma unroll
            for (int j = 0; j < 16; ++j) g[j] = 0.f;
            for (int k = 0; k < DD; ++k) {
                float t1 = s1[k * LD2 + r] * scof[pass * 32 + k];
                const float4* Wc = (const float4*)&s1[k * LD2 + cb];
                float4 w0 = Wc[0], w1 = Wc[1], w2 = Wc[2], w3 = Wc[3];
                g[0]+=t1*w0.x; g[1]+=t1*w0.y; g[2]+=t1*w0.z; g[3]+=t1*w0.w;
                g[4]+=t1*w1.x; g[5]+=t1*w1.y; g[6]+=t1*w1.z; g[7]+=t1*w1.w;
                g[8]+=t1*w2.x; g[9]+=t1*w2.y; g[10]+=t1*w2.z; g[11]+=t1*w2.w;
                g[12]+=t1*w3.x; g[13]+=t1*w3.y; g[14]+=t1*w3.z; g[15]+=t1*w3.w;
            }
            float* dst = (pass == 0) ? G : (pass == 1) ? Gs : Gis;
            float4* Db = (float4*)(dst + b * 1024 + lane * 16);
#pragma unroll
            for (int j4 = 0; j4 < 4; ++j4)
                Db[j4] = make_float4(g[4*j4], g[4*j4+1], g[4*j4+2], g[4*j4+3]);
        }

        // global convergence check by last-finishing batch
        __threadfence();
        if (lane == 0) {
            int r2 = atomicAdd(cnt_all, 1);
            if (r2 == BB - 1) {
                float nm = atomicAdd(norm_acc, 0.f);
                if (nm * (1.0f / BB) < TOLF) *done = 1;
                *norm_acc = 0.f;
                *cnt_all = 0;
                __threadfence();
            }
        }
    }
}

__global__ __launch_bounds__(256) void k5_out(const float* __restrict__ G, float* __restrict__ out) {
    int i = blockIdx.x * 256 + threadIdx.x;
    out[i] = G[i];
}

extern "C" void kernel_launch(void* const* d_in, const int* in_sizes, int n_in,
                              void* d_out, int out_size, void* d_ws, size_t ws_size,
                              hipStream_t stream) {
    const float* X = (const float*)d_in[0];
    float* ws = (float*)d_ws;
    float* G     = ws;                        // 65536
    float* Gs    = ws + 65536;                // 65536
    float* Gis   = ws + 2 * 65536;            // 65536
    float* Part  = ws + 3 * 65536;            // 1024 blocks * 1024 = 1048576
    float* norm_acc = ws + 3 * 65536 + 1048576;
    int*   cnt_all  = (int*)(norm_acc + 1);
    int*   done     = (int*)(norm_acc + 2);
    int*   cnt_b    = (int*)(norm_acc + 3);   // 64 ints
    size_t base_floats = (size_t)3 * 65536 + 1048576 + 80;  // aligned past counters
    // Vg: 64*1024 floats (256 KB) epilogue warm start; Vbuf: 64*512*1024 floats (128 MB) k2 warm start
    float* Vg   = (ws_size >= (base_floats + (size_t)BB * 1024) * sizeof(float))
                  ? (ws + base_floats) : nullptr;
    float* Vbuf = (ws_size >= (base_floats + (size_t)BB * 1024 + (size_t)BB * NN * 1024) * sizeof(float))
                  ? (ws + base_floats + (size_t)BB * 1024) : nullptr;

    k0_zero<<<64, 256, 0, stream>>>(G, done, norm_acc, cnt_all, cnt_b);
    k0_mean<<<512, 256, 0, stream>>>(X, G);
    k1_init<<<64, 64, 0, stream>>>(G, Gs, Gis, Vg);
    for (int it = 0; it < MAXIT; ++it) {
        int it_eff = (Vbuf != nullptr) ? it : 0;
        k2_log_acc<<<1024, 512, 0, stream>>>(X, G, Gs, Gis, Part, done, Vbuf, Vg,
                                             norm_acc, cnt_all, cnt_b, it_eff);
    }
    k5_out<<<256, 256, 0, stream>>>(G, (float*)d_out);
}

// Round 8
// 4520.574 us; speedup vs baseline: 1.1176x; 1.1176x over previous
//
#include <hip/hip_runtime.h>
#include <math.h>

#define BB 64
#define NN 512
#define DD 32
#define LD2 36           // sA leading dim (pad col 32 holds per-column tk)
#define LDG 32           // sG leading dim (broadcast/bank-r reads only)
#define JIT 1e-5f
#define TOLF 1e-4f
#define MAXIT 10

typedef float float2v __attribute__((ext_vector_type(2)));

__device__ __forceinline__ float2v efma(float2v a, float2v b, float2v c) {
    return __builtin_elementwise_fma(a, b, c);
}

// lane-pull via LDS permute unit; addr = src_lane<<2 (epilogue reductions only)
__device__ __forceinline__ float bpf(int addr, float v) {
    return __int_as_float(__builtin_amdgcn_ds_bpermute(addr, __float_as_int(v)));
}

// lane^16 via the LDS crossbar (fallback only)
__device__ __forceinline__ float swz16(float x) {
    return __int_as_float(__builtin_amdgcn_ds_swizzle(__float_as_int(x), 0x401F));
}

// cross-half (lane ^ 32) sum/max via VALU permlane32_swap
__device__ __forceinline__ float xhsum(float x) {
    unsigned u = __float_as_uint(x);
    auto r = __builtin_amdgcn_permlane32_swap(u, u, false, false);
    return __uint_as_float(r[0]) + __uint_as_float(r[1]);
}

__device__ __forceinline__ float xhmax(float x) {
    unsigned u = __float_as_uint(x);
    auto r = __builtin_amdgcn_permlane32_swap(u, u, false, false);
    return fmaxf(__uint_as_float(r[0]), __uint_as_float(r[1]));
}

__device__ __forceinline__ void wsync() {
    // wave-level LDS handoff (single-wave or per-wave-buffer use only)
    __asm__ volatile("s_waitcnt lgkmcnt(0)" ::: "memory");
}

template<int CTRL>
__device__ __forceinline__ float dppf(float x) {
    int i = __float_as_int(x);
    return __int_as_float(__builtin_amdgcn_update_dpp(i, i, CTRL, 0xF, 0xF, true));
}
// DPP ctrl semantics (GCN spec): row_shr:1=0x111 -> lane l receives lane l-1;
// row_shl:1=0x101 -> lane l receives lane l+1. (R7 had these swapped -> NaN.)
// quad_perm xor1=0xB1, xor2=0x4E, row_ror:4=0x124, row_ror:8=0x128

__device__ __forceinline__ float max16pair(float x) {
#if __has_builtin(__builtin_amdgcn_permlane16_swap)
    unsigned u = __float_as_uint(x);
    auto r = __builtin_amdgcn_permlane16_swap(u, u, false, false);
    return fmaxf(__uint_as_float(r[0]), __uint_as_float(r[1]));
#else
    return fmaxf(x, swz16(x));
#endif
}

// full-wave (64-lane) max reduction, VALU-only
__device__ __forceinline__ float redmax32(float x) {
    x = fmaxf(x, dppf<0xB1>(x));    // xor1
    x = fmaxf(x, dppf<0x4E>(x));    // xor2
    x = fmaxf(x, dppf<0x124>(x));   // ror4
    x = fmaxf(x, dppf<0x128>(x));   // ror8
    x = max16pair(x);               // 16 -> 32
    return xhmax(x);                // -> 64
}

// ---------------- one-sided (Hestenes) Jacobi, tournament (exchange-free) ----------------
// Lane holds BOTH columns of its rotation pair: u[32], v[32] (packed float2v[16]).
// 16 lanes = one matrix, wave = 4 matrices. Per round: dots + rotation fully
// lane-local (zero cross-lane); circle-method migration (ring of 31, u[0] fixed)
// via row_shr/row_shl DPP within each 16-lane group + cndmask edges. 31 rounds
// cover all 496 pairs and return columns to initial slots.
__device__ __forceinline__ void jac_quad(float2v U[16], float2v V[16],
                                         bool isL0, bool isL1, bool isL15,
                                         int maxsweep, float thr) {
#pragma unroll 1
    for (int sweep = 0; sweep < maxsweep; ++sweep) {
        float maxrel = 0.f;
#pragma unroll 1
        for (int rnd = 0; rnd < 31; ++rnd) {
            // lane-local dots (2-way split chains)
            float2v SU0 = {0.f,0.f}, SU1 = {0.f,0.f};
            float2v SV0 = {0.f,0.f}, SV1 = {0.f,0.f};
            float2v SC0 = {0.f,0.f}, SC1 = {0.f,0.f};
#pragma unroll
            for (int j = 0; j < 16; j += 2) {
                SU0 = efma(U[j],   U[j],   SU0);
                SU1 = efma(U[j+1], U[j+1], SU1);
                SV0 = efma(V[j],   V[j],   SV0);
                SV1 = efma(V[j+1], V[j+1], SV1);
                SC0 = efma(U[j],   V[j],   SC0);
                SC1 = efma(U[j+1], V[j+1], SC1);
            }
            float2v SU = SU0 + SU1, SV = SV0 + SV1, SC = SC0 + SC1;
            float gpp = SU.x + SU.y;
            float gqq = SV.x + SV.y;
            float gc  = SC.x + SC.y;
            float rel = gc * gc * __builtin_amdgcn_rcpf(gpp * gqq);
            maxrel = fmaxf(maxrel, rel);
            float tau = (gqq - gpp) * (0.5f * __builtin_amdgcn_rcpf(gc));
            float den = fabsf(tau) + __builtin_amdgcn_sqrtf(fmaf(tau, tau, 1.f));
            float tt  = copysignf(__builtin_amdgcn_rcpf(den), tau);
            tt = (rel > 1e-24f) ? tt : 0.f;
            float cs  = __builtin_amdgcn_rsqf(fmaf(tt, tt, 1.f));
            float sn  = tt * cs;
            float2v CS = {cs, cs}, SN = {sn, sn}, NS = {-sn, -sn};
#pragma unroll
            for (int j = 0; j < 16; ++j) {
                float2v uj = U[j], vj = V[j];
                U[j] = efma(NS, vj, uj * CS);   // u' = c*u - s*v
                V[j] = efma(SN, uj, vj * CS);   // v' = s*u + c*v
            }
            // circle-method migration within 16-lane group:
            // new_u[l]=u[l-1] (l>=2)  -> row_shr:1 (0x111)
            // new_u[1]=v[0]           -> row_shr:1 of v, at lane 1
            // u[0] fixed
            // new_v[l]=v[l+1] (l<=14) -> row_shl:1 (0x101)
            // new_v[15]=u[15]
#pragma unroll
            for (int j = 0; j < 16; ++j) {
                float ux = U[j].x, uy = U[j].y, vx = V[j].x, vy = V[j].y;
                float ax = dppf<0x111>(ux), ay = dppf<0x111>(uy);   // u[l-1]
                float bx = dppf<0x111>(vx), by = dppf<0x111>(vy);   // v[l-1] (lane1 -> v[0])
                float cx = dppf<0x101>(vx), cy = dppf<0x101>(vy);   // v[l+1]
                float nux = isL1 ? bx : ax;  nux = isL0 ? ux : nux;
                float nuy = isL1 ? by : ay;  nuy = isL0 ? uy : nuy;
                float nvx = isL15 ? ux : cx;
                float nvy = isL15 ? uy : cy;
                U[j].x = nux; U[j].y = nuy;
                V[j].x = nvx; V[j].y = nvy;
            }
        }
        maxrel = redmax32(maxrel);   // ties the wave's 4 matrices
        if (maxrel < thr) break;
    }
}

// C = A * B (32x32, both stride LD2). Wave-synchronous, in-place safe (single wave).
__device__ __forceinline__ void mm32w(const float* A, const float* B, float* C, int lane) {
    int r = lane >> 1, cb = (lane & 1) << 4;
    float acc[16];
#pragma unroll
    for (int j = 0; j < 16; ++j) acc[j] = 0.0f;
    for (int k = 0; k < DD; ++k) {
        float a = A[r * LD2 + k];
        const float4* Br = (const float4*)(B + k * LD2 + cb);
        float4 b0 = Br[0], b1 = Br[1], b2 = Br[2], b3 = Br[3];
        acc[0]  = fmaf(a, b0.x, acc[0]);  acc[1]  = fmaf(a, b0.y, acc[1]);
        acc[2]  = fmaf(a, b0.z, acc[2]);  acc[3]  = fmaf(a, b0.w, acc[3]);
        acc[4]  = fmaf(a, b1.x, acc[4]);  acc[5]  = fmaf(a, b1.y, acc[5]);
        acc[6]  = fmaf(a, b1.z, acc[6]);  acc[7]  = fmaf(a, b1.w, acc[7]);
        acc[8]  = fmaf(a, b2.x, acc[8]);  acc[9]  = fmaf(a, b2.y, acc[9]);
        acc[10] = fmaf(a, b2.z, acc[10]); acc[11] = fmaf(a, b2.w, acc[11]);
        acc[12] = fmaf(a, b3.x, acc[12]); acc[13] = fmaf(a, b3.y, acc[13]);
        acc[14] = fmaf(a, b3.z, acc[14]); acc[15] = fmaf(a, b3.w, acc[15]);
    }
    wsync();
    float4* Cr = (float4*)(C + r * LD2 + cb);
    Cr[0] = make_float4(acc[0],  acc[1],  acc[2],  acc[3]);
    Cr[1] = make_float4(acc[4],  acc[5],  acc[6],  acc[7]);
    Cr[2] = make_float4(acc[8],  acc[9],  acc[10], acc[11]);
    Cr[3] = make_float4(acc[12], acc[13], acc[14], acc[15]);
    wsync();
}

// ---------------- setup ----------------

__global__ __launch_bounds__(256) void k0_zero(float* __restrict__ G, int* __restrict__ done,
                                               float* __restrict__ norm_acc, int* __restrict__ cnt_all,
                                               int* __restrict__ cnt_b) {
    float4* Gb = (float4*)(G + blockIdx.x * 1024);
    Gb[threadIdx.x] = make_float4(0.f, 0.f, 0.f, 0.f);
    if (blockIdx.x == 0) {
        if (threadIdx.x == 0) { *done = 0; *norm_acc = 0.f; *cnt_all = 0; }
        if (threadIdx.x < BB) cnt_b[threadIdx.x] = 0;
    }
}

__global__ __launch_bounds__(256) void k0_mean(const float* __restrict__ X, float* __restrict__ G) {
    int blk = blockIdx.x;
    int b = blk >> 3, chunk = blk & 7;
    int t = threadIdx.x;
    const float4* Xb = (const float4*)(X + ((size_t)(b * NN + chunk * 64)) * 1024);
    float4 acc = make_float4(0.f, 0.f, 0.f, 0.f);
    for (int n = 0; n < 64; ++n) {
        float4 v = Xb[n * 256 + t];
        acc.x += v.x; acc.y += v.y; acc.z += v.z; acc.w += v.w;
    }
    const float inv = 1.0f / NN;
    float* Gb = G + b * 1024 + t * 4;
    atomicAdd(Gb + 0, acc.x * inv);
    atomicAdd(Gb + 1, acc.y * inv);
    atomicAdd(Gb + 2, acc.z * inv);
    atomicAdd(Gb + 3, acc.w * inv);
}

// ---------------- k1: initial eigh(G0) -> Gs, Gis; seed Vg (once) ----------------

__global__ __launch_bounds__(64) void k1_init(const float* __restrict__ G,
                                              float* __restrict__ Gs, float* __restrict__ Gis,
                                              float* __restrict__ Vg) {
    int b = blockIdx.x, lane = threadIdx.x;
    int l16 = lane & 15;
    bool isL0 = (l16 == 0), isL1 = (l16 == 1), isL15 = (l16 == 15);
    int r = lane >> 1, cb = (lane & 1) << 4;
    __shared__ __align__(16) float sW[DD * LD2];
    __shared__ float sc1[DD], sc2[DD];

    // all 4 groups duplicate the (symmetric) matrix; lane holds cols l16, 16+l16
    float2v U[16], V[16];
    {
        const float4* Gu = (const float4*)(G + b * 1024 + l16 * 32);
        const float4* Gv = (const float4*)(G + b * 1024 + (16 + l16) * 32);
#pragma unroll
        for (int j4 = 0; j4 < 8; ++j4) {
            float4 qu = Gu[j4], qv = Gv[j4];
            int e = 4 * j4;
            U[2*j4]   = (float2v){qu.x + ((e+0)==l16 ? JIT : 0.f), qu.y + ((e+1)==l16 ? JIT : 0.f)};
            U[2*j4+1] = (float2v){qu.z + ((e+2)==l16 ? JIT : 0.f), qu.w + ((e+3)==l16 ? JIT : 0.f)};
            V[2*j4]   = (float2v){qv.x + ((e+0)==16+l16 ? JIT : 0.f), qv.y + ((e+1)==16+l16 ? JIT : 0.f)};
            V[2*j4+1] = (float2v){qv.z + ((e+2)==16+l16 ? JIT : 0.f), qv.w + ((e+3)==16+l16 ? JIT : 0.f)};
        }
    }
    jac_quad(U, V, isL0, isL1, isL15, 10, 1e-12f);
    float2v NU = {0.f,0.f}, NV = {0.f,0.f};
#pragma unroll
    for (int j = 0; j < 16; ++j) { NU = efma(U[j], U[j], NU); NV = efma(V[j], V[j], NV); }
    float nu2 = NU.x + NU.y, nv2 = NV.x + NV.y;
    float lu = __builtin_amdgcn_sqrtf(nu2), lv = __builtin_amdgcn_sqrtf(nv2);
    float lcu = fmaxf(lu, JIT),            lcv = fmaxf(lv, JIT);
    float igu = __builtin_amdgcn_rcpf(nu2), igv = __builtin_amdgcn_rcpf(nv2);
    float c1u = __builtin_amdgcn_sqrtf(lcu) * igu, c1v = __builtin_amdgcn_sqrtf(lcv) * igv;
    float c2u = __builtin_amdgcn_rsqf(lcu) * igu,  c2v = __builtin_amdgcn_rsqf(lcv) * igv;
    if (Vg && lane < 16) {   // seed warm-start basis (group 0)
        float inu = __builtin_amdgcn_rsqf(nu2), inv_ = __builtin_amdgcn_rsqf(nv2);
        float4* Vpu = (float4*)(Vg + b * 1024 + l16 * 32);
        float4* Vpv = (float4*)(Vg + b * 1024 + (16 + l16) * 32);
#pragma unroll
        for (int j4 = 0; j4 < 8; ++j4) {
            Vpu[j4] = make_float4(U[2*j4].x*inu, U[2*j4].y*inu, U[2*j4+1].x*inu, U[2*j4+1].y*inu);
            Vpv[j4] = make_float4(V[2*j4].x*inv_, V[2*j4].y*inv_, V[2*j4+1].x*inv_, V[2*j4+1].y*inv_);
        }
    }
    if (lane < 16) {   // sW row c = eigvec column c
        float4* wpu = (float4*)&sW[l16 * LD2];
        float4* wpv = (float4*)&sW[(16 + l16) * LD2];
#pragma unroll
        for (int j4 = 0; j4 < 8; ++j4) {
            wpu[j4] = make_float4(U[2*j4].x, U[2*j4].y, U[2*j4+1].x, U[2*j4+1].y);
            wpv[j4] = make_float4(V[2*j4].x, V[2*j4].y, V[2*j4+1].x, V[2*j4+1].y);
        }
        sc1[l16] = c1u; sc1[16 + l16] = c1v;
        sc2[l16] = c2u; sc2[16 + l16] = c2v;
    }
    wsync();
    float a1[16], a2[16];
#pragma unroll
    for (int j = 0; j < 16; ++j) { a1[j] = 0.f; a2[j] = 0.f; }
    for (int k = 0; k < DD; ++k) {
        float wr = sW[k * LD2 + r];
        float t1 = wr * sc1[k], t2 = wr * sc2[k];
        const float4* Wc = (const float4*)&sW[k * LD2 + cb];
        float4 w0 = Wc[0], w1 = Wc[1], w2 = Wc[2], w3 = Wc[3];
        a1[0]+=t1*w0.x; a2[0]+=t2*w0.x;  a1[1]+=t1*w0.y; a2[1]+=t2*w0.y;
        a1[2]+=t1*w0.z; a2[2]+=t2*w0.z;  a1[3]+=t1*w0.w; a2[3]+=t2*w0.w;
        a1[4]+=t1*w1.x; a2[4]+=t2*w1.x;  a1[5]+=t1*w1.y; a2[5]+=t2*w1.y;
        a1[6]+=t1*w1.z; a2[6]+=t2*w1.z;  a1[7]+=t1*w1.w; a2[7]+=t2*w1.w;
        a1[8]+=t1*w2.x; a2[8]+=t2*w2.x;  a1[9]+=t1*w2.y; a2[9]+=t2*w2.y;
        a1[10]+=t1*w2.z; a2[10]+=t2*w2.z; a1[11]+=t1*w2.w; a2[11]+=t2*w2.w;
        a1[12]+=t1*w3.x; a2[12]+=t2*w3.x; a1[13]+=t1*w3.y; a2[13]+=t2*w3.y;
        a1[14]+=t1*w3.z; a2[14]+=t2*w3.z; a1[15]+=t1*w3.w; a2[15]+=t2*w3.w;
    }
    float4* Gsb  = (float4*)(Gs  + b * 1024 + lane * 16);
    float4* Gisb = (float4*)(Gis + b * 1024 + lane * 16);
#pragma unroll
    for (int j4 = 0; j4 < 4; ++j4) {
        Gsb[j4]  = make_float4(a1[4*j4], a1[4*j4+1], a1[4*j4+2], a1[4*j4+3]);
        Gisb[j4] = make_float4(a2[4*j4], a2[4*j4+1], a2[4*j4+2], a2[4*j4+3]);
    }
}

// ---------------- k2: hot kernel + fused per-b epilogue ----------------
// 1024 blocks x 8 waves; wave handles 4 matrices SIMULTANEOUSLY in one
// jac_quad call (16-lane group per matrix, 2 columns per lane).

__global__ __launch_bounds__(512) __attribute__((amdgpu_waves_per_eu(4, 8)))
void k2_log_acc(const float* __restrict__ X,
                float* G, float* Gs, float* Gis,
                float* __restrict__ Part,
                int* __restrict__ done,
                float* __restrict__ Vbuf,
                float* __restrict__ Vg,
                float* __restrict__ norm_acc,
                int* __restrict__ cnt_all,
                int* __restrict__ cnt_b,
                int it) {
    if (*done) return;
    int b = blockIdx.x >> 4, grp = blockIdx.x & 15;
    int wv = threadIdx.x >> 6, lane = threadIdx.x & 63;
    int g = lane >> 4, l16 = lane & 15;
    int c = lane & 31, h = lane >> 5;
    bool isL0 = (l16 == 0), isL1 = (l16 == 1), isL15 = (l16 == 15);
    int aself = lane << 2;

    __shared__ __align__(16) float sG[DD * LDG];           // 4096 B
    __shared__ __align__(16) float sAall[8][DD * LD2];     // 36864 B
    float* sA = sAall[wv];

    if (threadIdx.x < 256)
        ((float4*)sG)[threadIdx.x] = ((const float4*)(Gis + b * 1024))[threadIdx.x];
    __syncthreads();

    int r = lane >> 1, cb = (lane & 1) << 4;
    float dacc[16];
#pragma unroll
    for (int j = 0; j < 16; ++j) dacc[j] = 0.f;

    int nb = grp * 32 + wv * 4;
    float2v U[16], V[16];

#pragma unroll 1
    for (int mm = 0; mm < 4; ++mm) {
        int n = nb + mm;
        // ---- stage X[b,n] -> sA ----
        {
            const float4* Xv = (const float4*)(X + ((size_t)(b * NN + n)) * 1024);
            float4 v0 = Xv[lane * 4 + 0], v1 = Xv[lane * 4 + 1];
            float4 v2 = Xv[lane * 4 + 2], v3 = Xv[lane * 4 + 3];
            wsync();   // all prior readers of sA done
            int e = lane * 16;
            float* d0 = &sA[(e >> 5) * LD2 + (e & 31)];
            *((float4*)d0)        = v0;
            *((float4*)(d0 + 4))  = v1;
            *((float4*)(d0 + 8))  = v2;
            *((float4*)(d0 + 12)) = v3;
            wsync();
        }
        // ---- T = Gis * X ----
        {
            float acc[16];
#pragma unroll
            for (int j = 0; j < 16; ++j) acc[j] = 0.f;
            for (int k = 0; k < DD; ++k) {
                float av = sG[k * LDG + r];
                const float4* Br = (const float4*)(sA + k * LD2 + cb);
                float4 b0 = Br[0], b1 = Br[1], b2 = Br[2], b3 = Br[3];
                acc[0]  = fmaf(av, b0.x, acc[0]);  acc[1]  = fmaf(av, b0.y, acc[1]);
                acc[2]  = fmaf(av, b0.z, acc[2]);  acc[3]  = fmaf(av, b0.w, acc[3]);
                acc[4]  = fmaf(av, b1.x, acc[4]);  acc[5]  = fmaf(av, b1.y, acc[5]);
                acc[6]  = fmaf(av, b1.z, acc[6]);  acc[7]  = fmaf(av, b1.w, acc[7]);
                acc[8]  = fmaf(av, b2.x, acc[8]);  acc[9]  = fmaf(av, b2.y, acc[9]);
                acc[10] = fmaf(av, b2.z, acc[10]); acc[11] = fmaf(av, b2.w, acc[11]);
                acc[12] = fmaf(av, b3.x, acc[12]); acc[13] = fmaf(av, b3.y, acc[13]);
                acc[14] = fmaf(av, b3.z, acc[14]); acc[15] = fmaf(av, b3.w, acc[15]);
            }
            wsync();
            float4* Cr = (float4*)(sA + r * LD2 + cb);
            Cr[0] = make_float4(acc[0],  acc[1],  acc[2],  acc[3]);
            Cr[1] = make_float4(acc[4],  acc[5],  acc[6],  acc[7]);
            Cr[2] = make_float4(acc[8],  acc[9],  acc[10], acc[11]);
            Cr[3] = make_float4(acc[12], acc[13], acc[14], acc[15]);
            wsync();
        }
        // ---- A = T * Gis ----
        {
            float acc[16];
#pragma unroll
            for (int j = 0; j < 16; ++j) acc[j] = 0.f;
            for (int k = 0; k < DD; ++k) {
                float av = sA[r * LD2 + k];
                const float4* Br = (const float4*)(sG + k * LDG + cb);
                float4 b0 = Br[0], b1 = Br[1], b2 = Br[2], b3 = Br[3];
                acc[0]  = fmaf(av, b0.x, acc[0]);  acc[1]  = fmaf(av, b0.y, acc[1]);
                acc[2]  = fmaf(av, b0.z, acc[2]);  acc[3]  = fmaf(av, b0.w, acc[3]);
                acc[4]  = fmaf(av, b1.x, acc[4]);  acc[5]  = fmaf(av, b1.y, acc[5]);
                acc[6]  = fmaf(av, b1.z, acc[6]);  acc[7]  = fmaf(av, b1.w, acc[7]);
                acc[8]  = fmaf(av, b2.x, acc[8]);  acc[9]  = fmaf(av, b2.y, acc[9]);
                acc[10] = fmaf(av, b2.z, acc[10]); acc[11] = fmaf(av, b2.w, acc[11]);
                acc[12] = fmaf(av, b3.x, acc[12]); acc[13] = fmaf(av, b3.y, acc[13]);
                acc[14] = fmaf(av, b3.z, acc[14]); acc[15] = fmaf(av, b3.w, acc[15]);
            }
            wsync();
            float4* Cr = (float4*)(sA + r * LD2 + cb);
            Cr[0] = make_float4(acc[0],  acc[1],  acc[2],  acc[3]);
            Cr[1] = make_float4(acc[4],  acc[5],  acc[6],  acc[7]);
            Cr[2] = make_float4(acc[8],  acc[9],  acc[10], acc[11]);
            Cr[3] = make_float4(acc[12], acc[13], acc[14], acc[15]);
            wsync();
        }
        if (it == 0) {
            // owning group loads its symmetrized columns (scalar col+row reads)
            if (g == mm) {
#pragma unroll
                for (int j = 0; j < 16; ++j) {
                    int i0 = 2*j, i1 = 2*j + 1;
                    float cu0 = sA[i0 * LD2 + l16],        ru0 = sA[l16 * LD2 + i0];
                    float cu1 = sA[i1 * LD2 + l16],        ru1 = sA[l16 * LD2 + i1];
                    float cv0 = sA[i0 * LD2 + 16 + l16],   rv0 = sA[(16 + l16) * LD2 + i0];
                    float cv1 = sA[i1 * LD2 + 16 + l16],   rv1 = sA[(16 + l16) * LD2 + i1];
                    U[j].x = (i0 == l16)      ? ru0 + JIT : 0.5f * (cu0 + ru0);
                    U[j].y = (i1 == l16)      ? ru1 + JIT : 0.5f * (cu1 + ru1);
                    V[j].x = (i0 == 16 + l16) ? rv0 + JIT : 0.5f * (cv0 + rv0);
                    V[j].y = (i1 == 16 + l16) ? rv1 + JIT : 0.5f * (cv1 + rv1);
                }
            }
        } else {
            // cooperative W = (A + JIT I) * Vhat (all 64 lanes, half-split),
            // write W over sA (row c = column c), owning group reads its rows
            float vh[32];
            {
                const float4* Vp = (const float4*)(Vbuf + ((size_t)(b * NN + n)) * 1024 + c * 32);
#pragma unroll
                for (int j4 = 0; j4 < 8; ++j4) {
                    float4 t = Vp[j4];
                    vh[4*j4] = t.x; vh[4*j4+1] = t.y; vh[4*j4+2] = t.z; vh[4*j4+3] = t.w;
                }
            }
            float w[16];
#pragma unroll
            for (int i = 0; i < 16; ++i) {
                const float4* Ar = (const float4*)&sA[(16 * h + i) * LD2];
                float s = 0.f;
#pragma unroll
                for (int j4 = 0; j4 < 8; ++j4) {
                    float4 q = Ar[j4];
                    s = fmaf(q.x, vh[4*j4],   s);
                    s = fmaf(q.y, vh[4*j4+1], s);
                    s = fmaf(q.z, vh[4*j4+2], s);
                    s = fmaf(q.w, vh[4*j4+3], s);
                }
                float vhi = (h == 0) ? vh[i] : vh[16 + i];
                w[i] = fmaf(JIT, vhi, s);
            }
            wsync();   // all lanes' A reads done
            {
                float4* wp = (float4*)&sA[c * LD2 + 16 * h];
                wp[0] = make_float4(w[0],  w[1],  w[2],  w[3]);
                wp[1] = make_float4(w[4],  w[5],  w[6],  w[7]);
                wp[2] = make_float4(w[8],  w[9],  w[10], w[11]);
                wp[3] = make_float4(w[12], w[13], w[14], w[15]);
            }
            wsync();
            if (g == mm) {
                const float4* r0 = (const float4*)&sA[l16 * LD2];
                const float4* r1 = (const float4*)&sA[(16 + l16) * LD2];
#pragma unroll
                for (int j4 = 0; j4 < 8; ++j4) {
                    float4 q0 = r0[j4], q1 = r1[j4];
                    U[2*j4]   = (float2v){q0.x, q0.y};
                    U[2*j4+1] = (float2v){q0.z, q0.w};
                    V[2*j4]   = (float2v){q1.x, q1.y};
                    V[2*j4+1] = (float2v){q1.z, q1.w};
                }
            }
        }
    }

    jac_quad(U, V, isL0, isL1, isL15, 8, 1e-8f);

    // ---- extraction (lane-local, 2 columns) + V store ----
    float2v NU = {0.f,0.f}, NV = {0.f,0.f};
#pragma unroll
    for (int j = 0; j < 16; ++j) { NU = efma(U[j], U[j], NU); NV = efma(V[j], V[j], NV); }
    float nu2 = NU.x + NU.y, nv2 = NV.x + NV.y;
    float tku = 0.5f * logf(fmaxf(nu2, JIT * JIT)) * __builtin_amdgcn_rcpf(nu2);
    float tkv = 0.5f * logf(fmaxf(nv2, JIT * JIT)) * __builtin_amdgcn_rcpf(nv2);
    if (Vbuf) {
        int n = nb + g;
        float inu = __builtin_amdgcn_rsqf(nu2), inv_ = __builtin_amdgcn_rsqf(nv2);
        float4* Vpu = (float4*)(Vbuf + ((size_t)(b * NN + n)) * 1024 + l16 * 32);
        float4* Vpv = (float4*)(Vbuf + ((size_t)(b * NN + n)) * 1024 + (16 + l16) * 32);
#pragma unroll
        for (int j4 = 0; j4 < 8; ++j4) {
            Vpu[j4] = make_float4(U[2*j4].x*inu, U[2*j4].y*inu, U[2*j4+1].x*inu, U[2*j4+1].y*inu);
            Vpv[j4] = make_float4(V[2*j4].x*inv_, V[2*j4].y*inv_, V[2*j4+1].x*inv_, V[2*j4+1].y*inv_);
        }
    }
    // ---- per matrix: writeback W^T + tk, rebuild into dacc ----
#pragma unroll 1
    for (int mm = 0; mm < 4; ++mm) {
        wsync();   // prior readers of sA done
        if (g == mm) {
            float4* wpu = (float4*)&sA[l16 * LD2];
            float4* wpv = (float4*)&sA[(16 + l16) * LD2];
#pragma unroll
            for (int j4 = 0; j4 < 8; ++j4) {
                wpu[j4] = make_float4(U[2*j4].x, U[2*j4].y, U[2*j4+1].x, U[2*j4+1].y);
                wpv[j4] = make_float4(V[2*j4].x, V[2*j4].y, V[2*j4+1].x, V[2*j4+1].y);
            }
            sA[l16 * LD2 + 32] = tku;
            sA[(16 + l16) * LD2 + 32] = tkv;
        }
        wsync();
        for (int k = 0; k < DD; ++k) {
            float t1 = sA[k * LD2 + r] * sA[k * LD2 + 32];
            const float4* Wr = (const float4*)&sA[k * LD2 + cb];
            float4 w0 = Wr[0], w1 = Wr[1], w2 = Wr[2], w3 = Wr[3];
            dacc[0]  = fmaf(t1, w0.x, dacc[0]);  dacc[1]  = fmaf(t1, w0.y, dacc[1]);
            dacc[2]  = fmaf(t1, w0.z, dacc[2]);  dacc[3]  = fmaf(t1, w0.w, dacc[3]);
            dacc[4]  = fmaf(t1, w1.x, dacc[4]);  dacc[5]  = fmaf(t1, w1.y, dacc[5]);
            dacc[6]  = fmaf(t1, w1.z, dacc[6]);  dacc[7]  = fmaf(t1, w1.w, dacc[7]);
            dacc[8]  = fmaf(t1, w2.x, dacc[8]);  dacc[9]  = fmaf(t1, w2.y, dacc[9]);
            dacc[10] = fmaf(t1, w2.z, dacc[10]); dacc[11] = fmaf(t1, w2.w, dacc[11]);
            dacc[12] = fmaf(t1, w3.x, dacc[12]); dacc[13] = fmaf(t1, w3.y, dacc[13]);
            dacc[14] = fmaf(t1, w3.z, dacc[14]); dacc[15] = fmaf(t1, w3.w, dacc[15]);
        }
    }
    wsync();

    // ---- block reduction -> Part ----
    {
        float4* fp = (float4*)&sA[lane * 16];
        fp[0] = make_float4(dacc[0],  dacc[1],  dacc[2],  dacc[3]);
        fp[1] = make_float4(dacc[4],  dacc[5],  dacc[6],  dacc[7]);
        fp[2] = make_float4(dacc[8],  dacc[9],  dacc[10], dacc[11]);
        fp[3] = make_float4(dacc[12], dacc[13], dacc[14], dacc[15]);
    }
    __syncthreads();
    if (threadIdx.x < 256) {
        int t = threadIdx.x;
        float4 s0 = ((float4*)sAall[0])[t];
        float4 s1 = ((float4*)sAall[1])[t];
        float4 s2 = ((float4*)sAall[2])[t];
        float4 s3 = ((float4*)sAall[3])[t];
        float4 s4 = ((float4*)sAall[4])[t];
        float4 s5 = ((float4*)sAall[5])[t];
        float4 s6 = ((float4*)sAall[6])[t];
        float4 s7 = ((float4*)sAall[7])[t];
        float4 s;
        s.x = ((s0.x + s1.x) + (s2.x + s3.x)) + ((s4.x + s5.x) + (s6.x + s7.x));
        s.y = ((s0.y + s1.y) + (s2.y + s3.y)) + ((s4.y + s5.y) + (s6.y + s7.y));
        s.z = ((s0.z + s1.z) + (s2.z + s3.z)) + ((s4.z + s5.z) + (s6.z + s7.z));
        s.w = ((s0.w + s1.w) + (s2.w + s3.w)) + ((s4.w + s5.w) + (s6.w + s7.w));
        ((float4*)(Part + (size_t)blockIdx.x * 1024))[t] = s;
    }

    // ---- elect last-finishing block of this b ----
    int* winp = (int*)sG;   // sG dead now; reuse 4 bytes
    if (threadIdx.x == 0) *winp = 0;
    __syncthreads();        // Part stores complete (intra-block) + winp init
    if (threadIdx.x == 0) {
        __threadfence();    // release: our Part visible before count
        int ret = atomicAdd(&cnt_b[b], 1);
        if (ret == 15) { *winp = 1; cnt_b[b] = 0; }
    }
    __syncthreads();
    if (*winp == 0) return;
    if (threadIdx.x >= 64) return;
    __threadfence();        // acquire: other blocks' Part now visible

    // ==== fused epilogue, wave 0 only ====
    {
        float* s0 = sAall[0];
        float* s1 = sAall[1];
        float* s2 = sAall[2];
        float* scof = sAall[3];   // [0..31] G, [32..63] Gs, [64..95] Gis coefficients

        // Delta = sum of 16 partials / NN
        float d[16];
#pragma unroll
        for (int j = 0; j < 16; ++j) d[j] = 0.f;
#pragma unroll 1
        for (int gg = 0; gg < 16; ++gg) {
            const float4* P = (const float4*)(Part + (size_t)(b * 16 + gg) * 1024 + lane * 16);
            float4 p0 = P[0], p1 = P[1], p2 = P[2], p3 = P[3];
            d[0]+=p0.x; d[1]+=p0.y; d[2]+=p0.z; d[3]+=p0.w;
            d[4]+=p1.x; d[5]+=p1.y; d[6]+=p1.z; d[7]+=p1.w;
            d[8]+=p2.x; d[9]+=p2.y; d[10]+=p2.z; d[11]+=p2.w;
            d[12]+=p3.x; d[13]+=p3.y; d[14]+=p3.z; d[15]+=p3.w;
        }
        const float inv = 1.0f / NN;
        float sumsq = 0.f;
#pragma unroll
        for (int j = 0; j < 16; ++j) { d[j] *= inv; sumsq = fmaf(d[j], d[j], sumsq); }
#pragma unroll
        for (int sh = 1; sh <= 16; sh <<= 1) sumsq += bpf(aself ^ (sh << 2), sumsq);
        sumsq = xhsum(sumsq);
        if (lane == 0) atomicAdd(norm_acc, sqrtf(sumsq));

        wsync();
        // Delta -> s0
        {
            float4* dp = (float4*)&s0[r * LD2 + cb];
            dp[0] = make_float4(d[0],  d[1],  d[2],  d[3]);
            dp[1] = make_float4(d[4],  d[5],  d[6],  d[7]);
            dp[2] = make_float4(d[8],  d[9],  d[10], d[11]);
            dp[3] = make_float4(d[12], d[13], d[14], d[15]);
        }
        wsync();

        // expm_taylor order 5
        float outr[16];
#pragma unroll
        for (int j = 0; j < 16; ++j)
            outr[j] = ((cb + j) == r ? 1.0f : 0.0f) + d[j];
        float fac = 1.0f;
#pragma unroll 1
        for (int i = 2; i <= 5; ++i) {
            fac *= (float)i;
            float acc[16];
#pragma unroll
            for (int j = 0; j < 16; ++j) acc[j] = 0.f;
            const float* Xp = (i == 2) ? s0 : s1;
            for (int k = 0; k < DD; ++k) {
                float av = Xp[r * LD2 + k];
                const float4* Br = (const float4*)&s0[k * LD2 + cb];
                float4 b0 = Br[0], b1 = Br[1], b2 = Br[2], b3 = Br[3];
                acc[0]+=av*b0.x; acc[1]+=av*b0.y; acc[2]+=av*b0.z; acc[3]+=av*b0.w;
                acc[4]+=av*b1.x; acc[5]+=av*b1.y; acc[6]+=av*b1.z; acc[7]+=av*b1.w;
                acc[8]+=av*b2.x; acc[9]+=av*b2.y; acc[10]+=av*b2.z; acc[11]+=av*b2.w;
                acc[12]+=av*b3.x; acc[13]+=av*b3.y; acc[14]+=av*b3.z; acc[15]+=av*b3.w;
            }
            float invf = 1.0f / fac;
#pragma unroll
            for (int j = 0; j < 16; ++j) outr[j] = fmaf(acc[j], invf, outr[j]);
            wsync();
            float4* dp = (float4*)&s1[r * LD2 + cb];
            dp[0] = make_float4(acc[0],  acc[1],  acc[2],  acc[3]);
            dp[1] = make_float4(acc[4],  acc[5],  acc[6],  acc[7]);
            dp[2] = make_float4(acc[8],  acc[9],  acc[10], acc[11]);
            dp[3] = make_float4(acc[12], acc[13], acc[14], acc[15]);
            wsync();
        }
        // E -> s0; Gs_old -> s1
        {
            float4* dp = (float4*)&s0[r * LD2 + cb];
            dp[0] = make_float4(outr[0],  outr[1],  outr[2],  outr[3]);
            dp[1] = make_float4(outr[4],  outr[5],  outr[6],  outr[7]);
            dp[2] = make_float4(outr[8],  outr[9],  outr[10], outr[11]);
            dp[3] = make_float4(outr[12], outr[13], outr[14], outr[15]);
            const float4* Gsb = (const float4*)(Gs + b * 1024);
#pragma unroll
            for (int j4 = 0; j4 < 4; ++j4) {
                float4 v = Gsb[lane * 4 + j4];
                int e = lane * 16 + j4 * 4;
                *((float4*)&s1[(e >> 5) * LD2 + (e & 31)]) = v;
            }
        }
        wsync();
        mm32w(s1, s0, s2, lane);   // T = Gs * E
        mm32w(s2, s1, s0, lane);   // M = T * Gs

        // enforce_spd eigh (quad layout; all 4 groups duplicate the matrix)
        float2v AU[16], AV[16];
        if (Vg == nullptr) {
#pragma unroll
            for (int j = 0; j < 16; ++j) {
                int i0 = 2*j, i1 = 2*j + 1;
                float cu0 = s0[i0 * LD2 + l16],      ru0 = s0[l16 * LD2 + i0];
                float cu1 = s0[i1 * LD2 + l16],      ru1 = s0[l16 * LD2 + i1];
                float cv0 = s0[i0 * LD2 + 16 + l16], rv0 = s0[(16 + l16) * LD2 + i0];
                float cv1 = s0[i1 * LD2 + 16 + l16], rv1 = s0[(16 + l16) * LD2 + i1];
                AU[j].x = (i0 == l16)      ? ru0 + JIT : 0.5f * (cu0 + ru0);
                AU[j].y = (i1 == l16)      ? ru1 + JIT : 0.5f * (cu1 + ru1);
                AV[j].x = (i0 == 16 + l16) ? rv0 + JIT : 0.5f * (cv0 + rv0);
                AV[j].y = (i1 == 16 + l16) ? rv1 + JIT : 0.5f * (cv1 + rv1);
            }
        } else {
            // cooperative W = (M + JIT I) * Vg -> s2; groups read rows
            float vh[32];
            {
                const float4* Vp = (const float4*)(Vg + b * 1024 + c * 32);
#pragma unroll
                for (int j4 = 0; j4 < 8; ++j4) {
                    float4 t = Vp[j4];
                    vh[4*j4] = t.x; vh[4*j4+1] = t.y; vh[4*j4+2] = t.z; vh[4*j4+3] = t.w;
                }
            }
            float w[16];
#pragma unroll
            for (int i = 0; i < 16; ++i) {
                const float4* Mr = (const float4*)&s0[(16 * h + i) * LD2];
                float s = 0.f;
#pragma unroll
                for (int j4 = 0; j4 < 8; ++j4) {
                    float4 q = Mr[j4];
                    s = fmaf(q.x, vh[4*j4],   s);
                    s = fmaf(q.y, vh[4*j4+1], s);
                    s = fmaf(q.z, vh[4*j4+2], s);
                    s = fmaf(q.w, vh[4*j4+3], s);
                }
                float vhi = (h == 0) ? vh[i] : vh[16 + i];
                w[i] = fmaf(JIT, vhi, s);
            }
            wsync();
            {
                float4* wp = (float4*)&s2[c * LD2 + 16 * h];
                wp[0] = make_float4(w[0],  w[1],  w[2],  w[3]);
                wp[1] = make_float4(w[4],  w[5],  w[6],  w[7]);
                wp[2] = make_float4(w[8],  w[9],  w[10], w[11]);
                wp[3] = make_float4(w[12], w[13], w[14], w[15]);
            }
            wsync();
            const float4* r0 = (const float4*)&s2[l16 * LD2];
            const float4* r1 = (const float4*)&s2[(16 + l16) * LD2];
#pragma unroll
            for (int j4 = 0; j4 < 8; ++j4) {
                float4 q0 = r0[j4], q1 = r1[j4];
                AU[2*j4]   = (float2v){q0.x, q0.y};
                AU[2*j4+1] = (float2v){q0.z, q0.w};
                AV[2*j4]   = (float2v){q1.x, q1.y};
                AV[2*j4+1] = (float2v){q1.z, q1.w};
            }
        }
        jac_quad(AU, AV, isL0, isL1, isL15, 10, 1e-12f);
        float2v NU2 = {0.f,0.f}, NV2 = {0.f,0.f};
#pragma unroll
        for (int j = 0; j < 16; ++j) { NU2 = efma(AU[j], AU[j], NU2); NV2 = efma(AV[j], AV[j], NV2); }
        float mu2 = NU2.x + NU2.y, mv2 = NV2.x + NV2.y;
        float lu = __builtin_amdgcn_sqrtf(mu2), lv = __builtin_amdgcn_sqrtf(mv2);
        float clu = fmaxf(lu, JIT),             clv = fmaxf(lv, JIT);
        float igu = __builtin_amdgcn_rcpf(mu2), igv = __builtin_amdgcn_rcpf(mv2);
        float tgu = clu * igu,                  tgv = clv * igv;
        float shu = clu + JIT,                  shv = clv + JIT;
        float tsu = __builtin_amdgcn_sqrtf(shu) * igu, tsv = __builtin_amdgcn_sqrtf(shv) * igv;
        float tiu = __builtin_amdgcn_rsqf(shu) * igu,  tiv = __builtin_amdgcn_rsqf(shv) * igv;
        if (Vg && lane < 16) {
            float inu = __builtin_amdgcn_rsqf(mu2), inv_ = __builtin_amdgcn_rsqf(mv2);
            float4* Vpu = (float4*)(Vg + b * 1024 + l16 * 32);
            float4* Vpv = (float4*)(Vg + b * 1024 + (16 + l16) * 32);
#pragma unroll
            for (int j4 = 0; j4 < 8; ++j4) {
                Vpu[j4] = make_float4(AU[2*j4].x*inu, AU[2*j4].y*inu, AU[2*j4+1].x*inu, AU[2*j4+1].y*inu);
                Vpv[j4] = make_float4(AV[2*j4].x*inv_, AV[2*j4].y*inv_, AV[2*j4+1].x*inv_, AV[2*j4+1].y*inv_);
            }
        }
        wsync();
        // W -> s1 (row c = eigvec column c), coeffs -> scof
        if (lane < 16) {
            float4* wpu = (float4*)&s1[l16 * LD2];
            float4* wpv = (float4*)&s1[(16 + l16) * LD2];
#pragma unroll
            for (int j4 = 0; j4 < 8; ++j4) {
                wpu[j4] = make_float4(AU[2*j4].x, AU[2*j4].y, AU[2*j4+1].x, AU[2*j4+1].y);
                wpv[j4] = make_float4(AV[2*j4].x, AV[2*j4].y, AV[2*j4+1].x, AV[2*j4+1].y);
            }
            scof[l16] = tgu;      scof[16 + l16] = tgv;
            scof[32 + l16] = tsu; scof[48 + l16] = tsv;
            scof[64 + l16] = tiu; scof[80 + l16] = tiv;
        }
        wsync();
        // three low-register passes: G, Gs, Gis = W diag(coef) W^T
#pragma unroll 1
        for (int pass = 0; pass < 3; ++pass) {
            float gacc[16];
#pragma unroll
            for (int j = 0; j < 16; ++j) gacc[j] = 0.f;
            for (int k = 0; k < DD; ++k) {
                float t1 = s1[k * LD2 + r] * scof[pass * 32 + k];
                const float4* Wc = (const float4*)&s1[k * LD2 + cb];
                float4 w0 = Wc[0], w1 = Wc[1], w2 = Wc[2], w3 = Wc[3];
                gacc[0]+=t1*w0.x; gacc[1]+=t1*w0.y; gacc[2]+=t1*w0.z; gacc[3]+=t1*w0.w;
                gacc[4]+=t1*w1.x; gacc[5]+=t1*w1.y; gacc[6]+=t1*w1.z; gacc[7]+=t1*w1.w;
                gacc[8]+=t1*w2.x; gacc[9]+=t1*w2.y; gacc[10]+=t1*w2.z; gacc[11]+=t1*w2.w;
                gacc[12]+=t1*w3.x; gacc[13]+=t1*w3.y; gacc[14]+=t1*w3.z; gacc[15]+=t1*w3.w;
            }
            float* dst = (pass == 0) ? G : (pass == 1) ? Gs : Gis;
            float4* Db = (float4*)(dst + b * 1024 + lane * 16);
#pragma unroll
            for (int j4 = 0; j4 < 4; ++j4)
                Db[j4] = make_float4(gacc[4*j4], gacc[4*j4+1], gacc[4*j4+2], gacc[4*j4+3]);
        }

        // global convergence check by last-finishing batch
        __threadfence();
        if (lane == 0) {
            int r2 = atomicAdd(cnt_all, 1);
            if (r2 == BB - 1) {
                float nm = atomicAdd(norm_acc, 0.f);
                if (nm * (1.0f / BB) < TOLF) *done = 1;
                *norm_acc = 0.f;
                *cnt_all = 0;
                __threadfence();
            }
        }
    }
}

__global__ __launch_bounds__(256) void k5_out(const float* __restrict__ G, float* __restrict__ out) {
    int i = blockIdx.x * 256 + threadIdx.x;
    out[i] = G[i];
}

extern "C" void kernel_launch(void* const* d_in, const int* in_sizes, int n_in,
                              void* d_out, int out_size, void* d_ws, size_t ws_size,
                              hipStream_t stream) {
    const float* X = (const float*)d_in[0];
    float* ws = (float*)d_ws;
    float* G     = ws;                        // 65536
    float* Gs    = ws + 65536;                // 65536
    float* Gis   = ws + 2 * 65536;            // 65536
    float* Part  = ws + 3 * 65536;            // 1024 blocks * 1024 = 1048576
    float* norm_acc = ws + 3 * 65536 + 1048576;
    int*   cnt_all  = (int*)(norm_acc + 1);
    int*   done     = (int*)(norm_acc + 2);
    int*   cnt_b    = (int*)(norm_acc + 3);   // 64 ints
    size_t base_floats = (size_t)3 * 65536 + 1048576 + 80;  // aligned past counters
    // Vg: 64*1024 floats (256 KB) epilogue warm start; Vbuf: 64*512*1024 floats (128 MB) k2 warm start
    float* Vg   = (ws_size >= (base_floats + (size_t)BB * 1024) * sizeof(float))
                  ? (ws + base_floats) : nullptr;
    float* Vbuf = (ws_size >= (base_floats + (size_t)BB * 1024 + (size_t)BB * NN * 1024) * sizeof(float))
                  ? (ws + base_floats + (size_t)BB * 1024) : nullptr;

    k0_zero<<<64, 256, 0, stream>>>(G, done, norm_acc, cnt_all, cnt_b);
    k0_mean<<<512, 256, 0, stream>>>(X, G);
    k1_init<<<64, 64, 0, stream>>>(G, Gs, Gis, Vg);
    for (int it = 0; it < MAXIT; ++it) {
        int it_eff = (Vbuf != nullptr) ? it : 0;
        k2_log_acc<<<1024, 512, 0, stream>>>(X, G, Gs, Gis, Part, done, Vbuf, Vg,
                                             norm_acc, cnt_all, cnt_b, it_eff);
    }
    k5_out<<<256, 256, 0, stream>>>(G, (float*)d_out);
}

// Round 9
// 4124.816 us; speedup vs baseline: 1.2248x; 1.0959x over previous
//
#include <hip/hip_runtime.h>
#include <math.h>

#define BB 64
#define NN 512
#define DD 32
#define LD2 36           // sA leading dim (pad col 32 holds per-column tk)
#define LDG 32           // sG leading dim (broadcast/bank-r reads only)
#define JIT 1e-5f
#define TOLF 1e-4f
#define MAXIT 10
#define DSPLIT 10        // elems 0..DSPLIT-1 of M>=16 exchanges go via ds_swizzle

// lane-pull via LDS permute unit; addr = src_lane<<2 (epilogue reductions only)
__device__ __forceinline__ float bpf(int addr, float v) {
    return __int_as_float(__builtin_amdgcn_ds_bpermute(addr, __float_as_int(v)));
}

// lane^16 via the LDS crossbar (per-32-group xor16): 1 DS op, no VALU
__device__ __forceinline__ float swz16(float x) {
    return __int_as_float(__builtin_amdgcn_ds_swizzle(__float_as_int(x), 0x401F));
}

// cross-half (lane ^ 32) sum via VALU permlane32_swap: no DS pipe, no lgkmcnt.
__device__ __forceinline__ float xhsum(float x) {
    unsigned u = __float_as_uint(x);
    auto r = __builtin_amdgcn_permlane32_swap(u, u, false, false);
    return __uint_as_float(r[0]) + __uint_as_float(r[1]);
}

__device__ __forceinline__ float xhmax(float x) {
    unsigned u = __float_as_uint(x);
    auto r = __builtin_amdgcn_permlane32_swap(u, u, false, false);
    return fmaxf(__uint_as_float(r[0]), __uint_as_float(r[1]));
}

__device__ __forceinline__ void wsync() {
    // wave-level LDS handoff (single-wave or per-wave-buffer use only)
    __asm__ volatile("s_waitcnt lgkmcnt(0)" ::: "memory");
}

// ---- VALU lane-exchange primitives (DPP + permlane) ----
template<int CTRL>
__device__ __forceinline__ float dppf(float x) {
    int i = __float_as_int(x);
    return __int_as_float(__builtin_amdgcn_update_dpp(i, i, CTRL, 0xF, 0xF, true));
}
// DPP ctrl: quad_perm[1,0,3,2]=0xB1 (xor1), [2,3,0,1]=0x4E (xor2),
// [3,2,1,0]=0x1B (xor3), row_ror:4=0x124, row_ror:8=0x128 (xor8),
// row_mirror=0x140 (xor15), row_half_mirror=0x141 (xor7)

// value of lane^16 (permlane16_swap pair-select; ds_swizzle fallback)
__device__ __forceinline__ float part16(float x, bool hi16) {
#if __has_builtin(__builtin_amdgcn_permlane16_swap)
    unsigned u = __float_as_uint(x);
    auto r = __builtin_amdgcn_permlane16_swap(u, u, false, false);
    return hi16 ? __uint_as_float(r[0]) : __uint_as_float(r[1]);
#else
    return swz16(x);
#endif
}

__device__ __forceinline__ float max16pair(float x) {
#if __has_builtin(__builtin_amdgcn_permlane16_swap)
    unsigned u = __float_as_uint(x);
    auto r = __builtin_amdgcn_permlane16_swap(u, u, false, false);
    return fmaxf(__uint_as_float(r[0]), __uint_as_float(r[1]));
#else
    return fmaxf(x, swz16(x));
#endif
}

// value of lane^LOW for LOW in 0..15, composed from DPP XOR{1,2,3,7,8,15}
template<int LOW>
__device__ __forceinline__ float xorlane_lo(float x) {
    float v = x;
    if constexpr (LOW == 1)  v = dppf<0xB1>(v);
    else if constexpr (LOW == 2)  v = dppf<0x4E>(v);
    else if constexpr (LOW == 3)  v = dppf<0x1B>(v);
    else if constexpr (LOW == 4)  { v = dppf<0x141>(v); v = dppf<0x1B>(v); }  // 7^3
    else if constexpr (LOW == 5)  { v = dppf<0x141>(v); v = dppf<0x4E>(v); }  // 7^2
    else if constexpr (LOW == 6)  { v = dppf<0x141>(v); v = dppf<0xB1>(v); }  // 7^1
    else if constexpr (LOW == 7)  v = dppf<0x141>(v);
    else if constexpr (LOW == 8)  v = dppf<0x128>(v);
    else if constexpr (LOW == 9)  { v = dppf<0x128>(v); v = dppf<0xB1>(v); }
    else if constexpr (LOW == 10) { v = dppf<0x128>(v); v = dppf<0x4E>(v); }
    else if constexpr (LOW == 11) { v = dppf<0x128>(v); v = dppf<0x1B>(v); }
    else if constexpr (LOW == 12) { v = dppf<0x140>(v); v = dppf<0x1B>(v); }  // 15^3
    else if constexpr (LOW == 13) { v = dppf<0x140>(v); v = dppf<0x4E>(v); }  // 15^2
    else if constexpr (LOW == 14) { v = dppf<0x140>(v); v = dppf<0xB1>(v); }  // 15^1
    else if constexpr (LOW == 15) v = dppf<0x140>(v);
    return v;
}

// full-wave max reduction, VALU-only (+16-swap), no DS
__device__ __forceinline__ float redmax32(float x) {
    x = fmaxf(x, dppf<0xB1>(x));    // xor1
    x = fmaxf(x, dppf<0x4E>(x));    // xor2
    x = fmaxf(x, dppf<0x124>(x));   // ror4: covers remaining quads
    x = fmaxf(x, dppf<0x128>(x));   // ror8
    x = max16pair(x);               // rows of 16 -> 32
    return xhmax(x);                // -> 64
}

// ---------------- one-sided (Hestenes) Jacobi, two-pipe exchange ----------------
// One rotation of the XOR-m schedule. Exchange: M<16 pure DPP; M>=16 splits the
// ^16 leg across ds_swizzle (DS pipe, DSPLIT elems) and permlane (VALU, rest).
// Partner norm gp = lane-exchange of the freshly computed scalar gs
// (bit-identical to partner's own gs).
template<int M>
__device__ __forceinline__ void rot_step(float a[16], int c, bool hi16, float& maxrel) {
    constexpr int LOW = M & 15;
    float pa[16];
    if constexpr (M < 16) {
#pragma unroll
        for (int i = 0; i < 16; ++i) pa[i] = xorlane_lo<M>(a[i]);
    } else {
#pragma unroll
        for (int i = 0; i < 16; ++i) {
            float t = xorlane_lo<LOW>(a[i]);
            pa[i] = (i < DSPLIT) ? swz16(t) : part16(t, hi16);
        }
    }
    float gs = 0.f, gc = 0.f;
#pragma unroll
    for (int i = 0; i < 16; ++i) {
        gs = fmaf(a[i], a[i], gs);
        gc = fmaf(a[i], pa[i], gc);
    }
    gs = xhsum(gs);
    gc = xhsum(gc);
    float gp;
    if constexpr (M < 16) gp = xorlane_lo<M>(gs);
    else                  gp = swz16(xorlane_lo<LOW>(gs));
    bool isP = c < (c ^ M);
    float gpp = isP ? gs : gp;
    float gqq = isP ? gp : gs;
    float rel = gc * gc * __builtin_amdgcn_rcpf(gpp * gqq);
    maxrel = fmaxf(maxrel, rel);
    float tau = (gqq - gpp) * (0.5f * __builtin_amdgcn_rcpf(gc));
    float den = fabsf(tau) + __builtin_amdgcn_sqrtf(fmaf(tau, tau, 1.f));
    float tt  = copysignf(__builtin_amdgcn_rcpf(den), tau);
    tt = (rel > 1e-24f) ? tt : 0.f;
    float cs  = __builtin_amdgcn_rsqf(fmaf(tt, tt, 1.f));
    float sn  = tt * cs;
    float sg = isP ? -sn : sn;
#pragma unroll
    for (int i = 0; i < 16; ++i) a[i] = fmaf(sg, pa[i], cs * a[i]);
}

__device__ __forceinline__ void jac1(float a[16], int c, bool hi16,
                                     int maxsweep, float thr) {
#pragma unroll 1
    for (int sweep = 0; sweep < maxsweep; ++sweep) {
        float maxrel = 0.f;
        rot_step<1>(a, c, hi16, maxrel);  rot_step<2>(a, c, hi16, maxrel);
        rot_step<3>(a, c, hi16, maxrel);  rot_step<4>(a, c, hi16, maxrel);
        rot_step<5>(a, c, hi16, maxrel);  rot_step<6>(a, c, hi16, maxrel);
        rot_step<7>(a, c, hi16, maxrel);  rot_step<8>(a, c, hi16, maxrel);
        rot_step<9>(a, c, hi16, maxrel);  rot_step<10>(a, c, hi16, maxrel);
        rot_step<11>(a, c, hi16, maxrel); rot_step<12>(a, c, hi16, maxrel);
        rot_step<13>(a, c, hi16, maxrel); rot_step<14>(a, c, hi16, maxrel);
        rot_step<15>(a, c, hi16, maxrel); rot_step<16>(a, c, hi16, maxrel);
        rot_step<17>(a, c, hi16, maxrel); rot_step<18>(a, c, hi16, maxrel);
        rot_step<19>(a, c, hi16, maxrel); rot_step<20>(a, c, hi16, maxrel);
        rot_step<21>(a, c, hi16, maxrel); rot_step<22>(a, c, hi16, maxrel);
        rot_step<23>(a, c, hi16, maxrel); rot_step<24>(a, c, hi16, maxrel);
        rot_step<25>(a, c, hi16, maxrel); rot_step<26>(a, c, hi16, maxrel);
        rot_step<27>(a, c, hi16, maxrel); rot_step<28>(a, c, hi16, maxrel);
        rot_step<29>(a, c, hi16, maxrel); rot_step<30>(a, c, hi16, maxrel);
        rot_step<31>(a, c, hi16, maxrel);
        maxrel = redmax32(maxrel);
        if (maxrel < thr) break;
    }
}

// C = A * B (32x32, both stride LD2). Wave-synchronous, in-place safe (single wave).
__device__ __forceinline__ void mm32w(const float* A, const float* B, float* C, int lane) {
    int r = lane >> 1, cb = (lane & 1) << 4;
    float acc[16];
#pragma unroll
    for (int j = 0; j < 16; ++j) acc[j] = 0.0f;
    for (int k = 0; k < DD; ++k) {
        float a = A[r * LD2 + k];
        const float4* Br = (const float4*)(B + k * LD2 + cb);
        float4 b0 = Br[0], b1 = Br[1], b2 = Br[2], b3 = Br[3];
        acc[0]  = fmaf(a, b0.x, acc[0]);  acc[1]  = fmaf(a, b0.y, acc[1]);
        acc[2]  = fmaf(a, b0.z, acc[2]);  acc[3]  = fmaf(a, b0.w, acc[3]);
        acc[4]  = fmaf(a, b1.x, acc[4]);  acc[5]  = fmaf(a, b1.y, acc[5]);
        acc[6]  = fmaf(a, b1.z, acc[6]);  acc[7]  = fmaf(a, b1.w, acc[7]);
        acc[8]  = fmaf(a, b2.x, acc[8]);  acc[9]  = fmaf(a, b2.y, acc[9]);
        acc[10] = fmaf(a, b2.z, acc[10]); acc[11] = fmaf(a, b2.w, acc[11]);
        acc[12] = fmaf(a, b3.x, acc[12]); acc[13] = fmaf(a, b3.y, acc[13]);
        acc[14] = fmaf(a, b3.z, acc[14]); acc[15] = fmaf(a, b3.w, acc[15]);
    }
    wsync();
    float4* Cr = (float4*)(C + r * LD2 + cb);
    Cr[0] = make_float4(acc[0],  acc[1],  acc[2],  acc[3]);
    Cr[1] = make_float4(acc[4],  acc[5],  acc[6],  acc[7]);
    Cr[2] = make_float4(acc[8],  acc[9],  acc[10], acc[11]);
    Cr[3] = make_float4(acc[12], acc[13], acc[14], acc[15]);
    wsync();
}

// ---------------- setup ----------------

__global__ __launch_bounds__(256) void k0_zero(float* __restrict__ G, int* __restrict__ done,
                                               float* __restrict__ norm_acc, int* __restrict__ cnt_all,
                                               int* __restrict__ cnt_b) {
    float4* Gb = (float4*)(G + blockIdx.x * 1024);
    Gb[threadIdx.x] = make_float4(0.f, 0.f, 0.f, 0.f);
    if (blockIdx.x == 0) {
        if (threadIdx.x == 0) { *done = 0; *norm_acc = 0.f; *cnt_all = 0; }
        if (threadIdx.x < BB) cnt_b[threadIdx.x] = 0;
    }
}

__global__ __launch_bounds__(256) void k0_mean(const float* __restrict__ X, float* __restrict__ G) {
    int blk = blockIdx.x;
    int b = blk >> 3, chunk = blk & 7;
    int t = threadIdx.x;
    const float4* Xb = (const float4*)(X + ((size_t)(b * NN + chunk * 64)) * 1024);
    float4 acc = make_float4(0.f, 0.f, 0.f, 0.f);
    for (int n = 0; n < 64; ++n) {
        float4 v = Xb[n * 256 + t];
        acc.x += v.x; acc.y += v.y; acc.z += v.z; acc.w += v.w;
    }
    const float inv = 1.0f / NN;
    float* Gb = G + b * 1024 + t * 4;
    atomicAdd(Gb + 0, acc.x * inv);
    atomicAdd(Gb + 1, acc.y * inv);
    atomicAdd(Gb + 2, acc.z * inv);
    atomicAdd(Gb + 3, acc.w * inv);
}

// ---------------- k1: initial eigh(G0) -> Gs, Gis; seed Vg (once) ----------------

__global__ __launch_bounds__(64) void k1_init(const float* __restrict__ G,
                                              float* __restrict__ Gs, float* __restrict__ Gis,
                                              float* __restrict__ Vg) {
    int b = blockIdx.x, lane = threadIdx.x;
    int c = lane & 31, h = lane >> 5;
    bool hi16 = (lane & 16) != 0;
    int r = lane >> 1, cb = (lane & 1) << 4;
    __shared__ __align__(16) float sW[DD * LD2];
    __shared__ float sc1[DD], sc2[DD];

    float a[16];
    {
        const float4* Gc = (const float4*)(G + b * 1024 + c * 32 + 16 * h);
        float4 v0 = Gc[0], v1 = Gc[1], v2 = Gc[2], v3 = Gc[3];
        a[0]=v0.x; a[1]=v0.y; a[2]=v0.z; a[3]=v0.w;
        a[4]=v1.x; a[5]=v1.y; a[6]=v1.z; a[7]=v1.w;
        a[8]=v2.x; a[9]=v2.y; a[10]=v2.z; a[11]=v2.w;
        a[12]=v3.x; a[13]=v3.y; a[14]=v3.z; a[15]=v3.w;
#pragma unroll
        for (int i = 0; i < 16; ++i)
            if (16 * h + i == c) a[i] += JIT;   // _safe_eigh jitter
    }
    jac1(a, c, hi16, 10, 1e-12f);
    float gs2 = 0.f;
#pragma unroll
    for (int i = 0; i < 16; ++i) gs2 = fmaf(a[i], a[i], gs2);
    gs2 = xhsum(gs2);
    float l  = __builtin_amdgcn_sqrtf(gs2);
    float lc = fmaxf(l, JIT);
    float ig = __builtin_amdgcn_rcpf(gs2);
    float c1 = __builtin_amdgcn_sqrtf(lc) * ig;   // sqrt(clip(lam)) / lam^2
    float c2 = __builtin_amdgcn_rsqf(lc) * ig;    // 1/sqrt(clip(lam)) / lam^2
    if (Vg) {   // seed warm-start basis for the fused epilogue
        float inl = __builtin_amdgcn_rsqf(gs2);
        float4* Vp = (float4*)(Vg + b * 1024 + c * 32 + 16 * h);
        Vp[0] = make_float4(a[0]*inl,  a[1]*inl,  a[2]*inl,  a[3]*inl);
        Vp[1] = make_float4(a[4]*inl,  a[5]*inl,  a[6]*inl,  a[7]*inl);
        Vp[2] = make_float4(a[8]*inl,  a[9]*inl,  a[10]*inl, a[11]*inl);
        Vp[3] = make_float4(a[12]*inl, a[13]*inl, a[14]*inl, a[15]*inl);
    }
    {
        float4* wp = (float4*)&sW[c * LD2 + 16 * h];
        wp[0] = make_float4(a[0],  a[1],  a[2],  a[3]);
        wp[1] = make_float4(a[4],  a[5],  a[6],  a[7]);
        wp[2] = make_float4(a[8],  a[9],  a[10], a[11]);
        wp[3] = make_float4(a[12], a[13], a[14], a[15]);
        if (h == 0) { sc1[c] = c1; sc2[c] = c2; }
    }
    wsync();
    float a1[16], a2[16];
#pragma unroll
    for (int j = 0; j < 16; ++j) { a1[j] = 0.f; a2[j] = 0.f; }
    for (int k = 0; k < DD; ++k) {
        float wr = sW[k * LD2 + r];
        float t1 = wr * sc1[k], t2 = wr * sc2[k];
        const float4* Wc = (const float4*)&sW[k * LD2 + cb];
        float4 w0 = Wc[0], w1 = Wc[1], w2 = Wc[2], w3 = Wc[3];
        a1[0]+=t1*w0.x; a2[0]+=t2*w0.x;  a1[1]+=t1*w0.y; a2[1]+=t2*w0.y;
        a1[2]+=t1*w0.z; a2[2]+=t2*w0.z;  a1[3]+=t1*w0.w; a2[3]+=t2*w0.w;
        a1[4]+=t1*w1.x; a2[4]+=t2*w1.x;  a1[5]+=t1*w1.y; a2[5]+=t2*w1.y;
        a1[6]+=t1*w1.z; a2[6]+=t2*w1.z;  a1[7]+=t1*w1.w; a2[7]+=t2*w1.w;
        a1[8]+=t1*w2.x; a2[8]+=t2*w2.x;  a1[9]+=t1*w2.y; a2[9]+=t2*w2.y;
        a1[10]+=t1*w2.z; a2[10]+=t2*w2.z; a1[11]+=t1*w2.w; a2[11]+=t2*w2.w;
        a1[12]+=t1*w3.x; a2[12]+=t2*w3.x; a1[13]+=t1*w3.y; a2[13]+=t2*w3.y;
        a1[14]+=t1*w3.z; a2[14]+=t2*w3.z; a1[15]+=t1*w3.w; a2[15]+=t2*w3.w;
    }
    float4* Gsb  = (float4*)(Gs  + b * 1024 + lane * 16);
    float4* Gisb = (float4*)(Gis + b * 1024 + lane * 16);
#pragma unroll
    for (int j4 = 0; j4 < 4; ++j4) {
        Gsb[j4]  = make_float4(a1[4*j4], a1[4*j4+1], a1[4*j4+2], a1[4*j4+3]);
        Gisb[j4] = make_float4(a2[4*j4], a2[4*j4+1], a2[4*j4+2], a2[4*j4+3]);
    }
}

// ---------------- k2: hot kernel + fused per-b epilogue ----------------
// 1024 blocks x 8 waves; wave handles 4 matrices. launch_bounds (512,4):
// VGPR cap 128. maxsweep 6 (was 8): thr=1e-8 unchanged, so typical matrices
// are identical; only the hard tail stops earlier (absmax margin is 400x).

__global__ __launch_bounds__(512, 4) void k2_log_acc(const float* __restrict__ X,
                                                     float* G, float* Gs, float* Gis,
                                                     float* __restrict__ Part,
                                                     int* __restrict__ done,
                                                     float* __restrict__ Vbuf,
                                                     float* __restrict__ Vg,
                                                     float* __restrict__ norm_acc,
                                                     int* __restrict__ cnt_all,
                                                     int* __restrict__ cnt_b,
                                                     int it) {
    if (*done) return;
    int b = blockIdx.x >> 4, grp = blockIdx.x & 15;
    int wv = threadIdx.x >> 6, lane = threadIdx.x & 63;
    int c = lane & 31, h = lane >> 5;
    bool hi16 = (lane & 16) != 0;
    int aself = lane << 2;

    __shared__ __align__(16) float sG[DD * LDG];           // 4096 B
    __shared__ __align__(16) float sAall[8][DD * LD2];     // 36864 B
    float* sA = sAall[wv];

    if (threadIdx.x < 256)
        ((float4*)sG)[threadIdx.x] = ((const float4*)(Gis + b * 1024))[threadIdx.x];
    __syncthreads();

    int r = lane >> 1, cb = (lane & 1) << 4;
    float dacc[16];
#pragma unroll
    for (int j = 0; j < 16; ++j) dacc[j] = 0.f;

#pragma unroll 1
    for (int nn = 0; nn < 4; ++nn) {
        int n = grp * 32 + wv * 4 + nn;
        // ---- stage X[b,n] -> sA ----
        {
            const float4* Xv = (const float4*)(X + ((size_t)(b * NN + n)) * 1024);
            float4 v0 = Xv[lane * 4 + 0], v1 = Xv[lane * 4 + 1];
            float4 v2 = Xv[lane * 4 + 2], v3 = Xv[lane * 4 + 3];
            wsync();   // all prior readers of sA done
            int e = lane * 16;
            float* d0 = &sA[(e >> 5) * LD2 + (e & 31)];
            *((float4*)d0)        = v0;
            *((float4*)(d0 + 4))  = v1;
            *((float4*)(d0 + 8))  = v2;
            *((float4*)(d0 + 12)) = v3;
            wsync();
        }
        // ---- T = Gis * X (A-operand transposed read from sG: conflict-free) ----
        {
            float acc[16];
#pragma unroll
            for (int j = 0; j < 16; ++j) acc[j] = 0.f;
            for (int k = 0; k < DD; ++k) {
                float av = sG[k * LDG + r];
                const float4* Br = (const float4*)(sA + k * LD2 + cb);
                float4 b0 = Br[0], b1 = Br[1], b2 = Br[2], b3 = Br[3];
                acc[0]  = fmaf(av, b0.x, acc[0]);  acc[1]  = fmaf(av, b0.y, acc[1]);
                acc[2]  = fmaf(av, b0.z, acc[2]);  acc[3]  = fmaf(av, b0.w, acc[3]);
                acc[4]  = fmaf(av, b1.x, acc[4]);  acc[5]  = fmaf(av, b1.y, acc[5]);
                acc[6]  = fmaf(av, b1.z, acc[6]);  acc[7]  = fmaf(av, b1.w, acc[7]);
                acc[8]  = fmaf(av, b2.x, acc[8]);  acc[9]  = fmaf(av, b2.y, acc[9]);
                acc[10] = fmaf(av, b2.z, acc[10]); acc[11] = fmaf(av, b2.w, acc[11]);
                acc[12] = fmaf(av, b3.x, acc[12]); acc[13] = fmaf(av, b3.y, acc[13]);
                acc[14] = fmaf(av, b3.z, acc[14]); acc[15] = fmaf(av, b3.w, acc[15]);
            }
            wsync();
            float4* Cr = (float4*)(sA + r * LD2 + cb);
            Cr[0] = make_float4(acc[0],  acc[1],  acc[2],  acc[3]);
            Cr[1] = make_float4(acc[4],  acc[5],  acc[6],  acc[7]);
            Cr[2] = make_float4(acc[8],  acc[9],  acc[10], acc[11]);
            Cr[3] = make_float4(acc[12], acc[13], acc[14], acc[15]);
            wsync();
        }
        // ---- A = T * Gis ----
        {
            float acc[16];
#pragma unroll
            for (int j = 0; j < 16; ++j) acc[j] = 0.f;
            for (int k = 0; k < DD; ++k) {
                float av = sA[r * LD2 + k];
                const float4* Br = (const float4*)(sG + k * LDG + cb);
                float4 b0 = Br[0], b1 = Br[1], b2 = Br[2], b3 = Br[3];
                acc[0]  = fmaf(av, b0.x, acc[0]);  acc[1]  = fmaf(av, b0.y, acc[1]);
                acc[2]  = fmaf(av, b0.z, acc[2]);  acc[3]  = fmaf(av, b0.w, acc[3]);
                acc[4]  = fmaf(av, b1.x, acc[4]);  acc[5]  = fmaf(av, b1.y, acc[5]);
                acc[6]  = fmaf(av, b1.z, acc[6]);  acc[7]  = fmaf(av, b1.w, acc[7]);
                acc[8]  = fmaf(av, b2.x, acc[8]);  acc[9]  = fmaf(av, b2.y, acc[9]);
                acc[10] = fmaf(av, b2.z, acc[10]); acc[11] = fmaf(av, b2.w, acc[11]);
                acc[12] = fmaf(av, b3.x, acc[12]); acc[13] = fmaf(av, b3.y, acc[13]);
                acc[14] = fmaf(av, b3.z, acc[14]); acc[15] = fmaf(av, b3.w, acc[15]);
            }
            wsync();
            float4* Cr = (float4*)(sA + r * LD2 + cb);
            Cr[0] = make_float4(acc[0],  acc[1],  acc[2],  acc[3]);
            Cr[1] = make_float4(acc[4],  acc[5],  acc[6],  acc[7]);
            Cr[2] = make_float4(acc[8],  acc[9],  acc[10], acc[11]);
            Cr[3] = make_float4(acc[12], acc[13], acc[14], acc[15]);
            wsync();
        }
        // ---- initial W columns: cold (A cols, symmetrized) or warm (A * V_prev) ----
        float a[16];
        if (it == 0) {
            const float4* cp = (const float4*)&sA[c * LD2 + 16 * h];
            float4 t0 = cp[0], t1 = cp[1], t2 = cp[2], t3 = cp[3];
            float tr[16] = { t0.x,t0.y,t0.z,t0.w, t1.x,t1.y,t1.z,t1.w,
                             t2.x,t2.y,t2.z,t2.w, t3.x,t3.y,t3.z,t3.w };
#pragma unroll
            for (int i = 0; i < 16; ++i) {
                int row = 16 * h + i;
                float v = 0.5f * (sA[row * LD2 + c] + tr[i]);
                if (row == c) v = tr[i] + JIT;
                a[i] = v;
            }
        } else {
            // w_c = (A + JIT I) * vhat_prev_c ; vhat in registers, A rows broadcast from LDS
            float v[32];
            {
                const float4* Vp = (const float4*)(Vbuf + ((size_t)(b * NN + n)) * 1024 + c * 32);
#pragma unroll
                for (int j4 = 0; j4 < 8; ++j4) {
                    float4 t = Vp[j4];
                    v[4*j4] = t.x; v[4*j4+1] = t.y; v[4*j4+2] = t.z; v[4*j4+3] = t.w;
                }
            }
#pragma unroll
            for (int i = 0; i < 16; ++i) {
                const float4* Ar = (const float4*)&sA[(16 * h + i) * LD2];
                float s = 0.f;
#pragma unroll
                for (int j4 = 0; j4 < 8; ++j4) {
                    float4 q = Ar[j4];
                    s = fmaf(q.x, v[4*j4],   s);
                    s = fmaf(q.y, v[4*j4+1], s);
                    s = fmaf(q.z, v[4*j4+2], s);
                    s = fmaf(q.w, v[4*j4+3], s);
                }
                a[i] = fmaf(JIT, v[16 * h + i], s);
            }
        }

        jac1(a, c, hi16, 6, 1e-8f);

        // ---- eigen extraction + V store + rebuild ----
        {
            float gs2 = 0.f;
#pragma unroll
            for (int i = 0; i < 16; ++i) gs2 = fmaf(a[i], a[i], gs2);
            gs2 = xhsum(gs2);
            float gs2c = fmaxf(gs2, JIT * JIT);
            float tk = 0.5f * logf(gs2c) * __builtin_amdgcn_rcpf(gs2);
            if (Vbuf) {   // store normalized eigenvectors for next iteration's warm start
                float inl = __builtin_amdgcn_rsqf(gs2);
                float4* Vp = (float4*)(Vbuf + ((size_t)(b * NN + n)) * 1024 + c * 32 + 16 * h);
                Vp[0] = make_float4(a[0]*inl,  a[1]*inl,  a[2]*inl,  a[3]*inl);
                Vp[1] = make_float4(a[4]*inl,  a[5]*inl,  a[6]*inl,  a[7]*inl);
                Vp[2] = make_float4(a[8]*inl,  a[9]*inl,  a[10]*inl, a[11]*inl);
                Vp[3] = make_float4(a[12]*inl, a[13]*inl, a[14]*inl, a[15]*inl);
            }
            wsync();   // prior readers of sA done
            float4* wp = (float4*)&sA[c * LD2 + 16 * h];
            wp[0] = make_float4(a[0],  a[1],  a[2],  a[3]);
            wp[1] = make_float4(a[4],  a[5],  a[6],  a[7]);
            wp[2] = make_float4(a[8],  a[9],  a[10], a[11]);
            wp[3] = make_float4(a[12], a[13], a[14], a[15]);
            if (h == 0) sA[c * LD2 + 32] = tk;          // tk in row padding
            wsync();
            for (int k = 0; k < DD; ++k) {
                float t1 = sA[k * LD2 + r] * sA[k * LD2 + 32];
                const float4* Wr = (const float4*)&sA[k * LD2 + cb];
                float4 w0 = Wr[0], w1 = Wr[1], w2 = Wr[2], w3 = Wr[3];
                dacc[0]  = fmaf(t1, w0.x, dacc[0]);  dacc[1]  = fmaf(t1, w0.y, dacc[1]);
                dacc[2]  = fmaf(t1, w0.z, dacc[2]);  dacc[3]  = fmaf(t1, w0.w, dacc[3]);
                dacc[4]  = fmaf(t1, w1.x, dacc[4]);  dacc[5]  = fmaf(t1, w1.y, dacc[5]);
                dacc[6]  = fmaf(t1, w1.z, dacc[6]);  dacc[7]  = fmaf(t1, w1.w, dacc[7]);
                dacc[8]  = fmaf(t1, w2.x, dacc[8]);  dacc[9]  = fmaf(t1, w2.y, dacc[9]);
                dacc[10] = fmaf(t1, w2.z, dacc[10]); dacc[11] = fmaf(t1, w2.w, dacc[11]);
                dacc[12] = fmaf(t1, w3.x, dacc[12]); dacc[13] = fmaf(t1, w3.y, dacc[13]);
                dacc[14] = fmaf(t1, w3.z, dacc[14]); dacc[15] = fmaf(t1, w3.w, dacc[15]);
            }
        }
    }
    wsync();

    // ---- block reduction -> Part ----
    {
        float4* fp = (float4*)&sA[lane * 16];
        fp[0] = make_float4(dacc[0],  dacc[1],  dacc[2],  dacc[3]);
        fp[1] = make_float4(dacc[4],  dacc[5],  dacc[6],  dacc[7]);
        fp[2] = make_float4(dacc[8],  dacc[9],  dacc[10], dacc[11]);
        fp[3] = make_float4(dacc[12], dacc[13], dacc[14], dacc[15]);
    }
    __syncthreads();
    if (threadIdx.x < 256) {
        int t = threadIdx.x;
        float4 s0 = ((float4*)sAall[0])[t];
        float4 s1 = ((float4*)sAall[1])[t];
        float4 s2 = ((float4*)sAall[2])[t];
        float4 s3 = ((float4*)sAall[3])[t];
        float4 s4 = ((float4*)sAall[4])[t];
        float4 s5 = ((float4*)sAall[5])[t];
        float4 s6 = ((float4*)sAall[6])[t];
        float4 s7 = ((float4*)sAall[7])[t];
        float4 s;
        s.x = ((s0.x + s1.x) + (s2.x + s3.x)) + ((s4.x + s5.x) + (s6.x + s7.x));
        s.y = ((s0.y + s1.y) + (s2.y + s3.y)) + ((s4.y + s5.y) + (s6.y + s7.y));
        s.z = ((s0.z + s1.z) + (s2.z + s3.z)) + ((s4.z + s5.z) + (s6.z + s7.z));
        s.w = ((s0.w + s1.w) + (s2.w + s3.w)) + ((s4.w + s5.w) + (s6.w + s7.w));
        ((float4*)(Part + (size_t)blockIdx.x * 1024))[t] = s;
    }

    // ---- elect last-finishing block of this b ----
    int* winp = (int*)sG;   // sG dead now; reuse 4 bytes
    if (threadIdx.x == 0) *winp = 0;
    __syncthreads();        // Part stores complete (intra-block) + winp init
    if (threadIdx.x == 0) {
        __threadfence();    // release: our Part visible before count
        int ret = atomicAdd(&cnt_b[b], 1);
        if (ret == 15) { *winp = 1; cnt_b[b] = 0; }
    }
    __syncthreads();
    if (*winp == 0) return;
    if (threadIdx.x >= 64) return;
    __threadfence();        // acquire: other blocks' Part now visible

    // ==== fused epilogue, wave 0 only ====
    {
        float* s0 = sAall[0];
        float* s1 = sAall[1];
        float* s2 = sAall[2];
        float* scof = sAall[3];   // [0..31] G, [32..63] Gs, [64..95] Gis coefficients

        // Delta = sum of 16 partials / NN
        float d[16];
#pragma unroll
        for (int j = 0; j < 16; ++j) d[j] = 0.f;
#pragma unroll 1
        for (int g = 0; g < 16; ++g) {
            const float4* P = (const float4*)(Part + (size_t)(b * 16 + g) * 1024 + lane * 16);
            float4 p0 = P[0], p1 = P[1], p2 = P[2], p3 = P[3];
            d[0]+=p0.x; d[1]+=p0.y; d[2]+=p0.z; d[3]+=p0.w;
            d[4]+=p1.x; d[5]+=p1.y; d[6]+=p1.z; d[7]+=p1.w;
            d[8]+=p2.x; d[9]+=p2.y; d[10]+=p2.z; d[11]+=p2.w;
            d[12]+=p3.x; d[13]+=p3.y; d[14]+=p3.z; d[15]+=p3.w;
        }
        const float inv = 1.0f / NN;
        float sumsq = 0.f;
#pragma unroll
        for (int j = 0; j < 16; ++j) { d[j] *= inv; sumsq = fmaf(d[j], d[j], sumsq); }
#pragma unroll
        for (int sh = 1; sh <= 16; sh <<= 1) sumsq += bpf(aself ^ (sh << 2), sumsq);
        sumsq = xhsum(sumsq);
        if (lane == 0) atomicAdd(norm_acc, sqrtf(sumsq));

        wsync();   // all waves' reduction reads of sAall are done (post-barrier); safe to overwrite
        // Delta -> s0
        {
            float4* dp = (float4*)&s0[r * LD2 + cb];
            dp[0] = make_float4(d[0],  d[1],  d[2],  d[3]);
            dp[1] = make_float4(d[4],  d[5],  d[6],  d[7]);
            dp[2] = make_float4(d[8],  d[9],  d[10], d[11]);
            dp[3] = make_float4(d[12], d[13], d[14], d[15]);
        }
        wsync();

        // expm_taylor order 5
        float outr[16];
#pragma unroll
        for (int j = 0; j < 16; ++j)
            outr[j] = ((cb + j) == r ? 1.0f : 0.0f) + d[j];
        float fac = 1.0f;
#pragma unroll 1
        for (int i = 2; i <= 5; ++i) {
            fac *= (float)i;
            float acc[16];
#pragma unroll
            for (int j = 0; j < 16; ++j) acc[j] = 0.f;
            const float* Xp = (i == 2) ? s0 : s1;
            for (int k = 0; k < DD; ++k) {
                float av = Xp[r * LD2 + k];
                const float4* Br = (const float4*)&s0[k * LD2 + cb];
                float4 b0 = Br[0], b1 = Br[1], b2 = Br[2], b3 = Br[3];
                acc[0]+=av*b0.x; acc[1]+=av*b0.y; acc[2]+=av*b0.z; acc[3]+=av*b0.w;
                acc[4]+=av*b1.x; acc[5]+=av*b1.y; acc[6]+=av*b1.z; acc[7]+=av*b1.w;
                acc[8]+=av*b2.x; acc[9]+=av*b2.y; acc[10]+=av*b2.z; acc[11]+=av*b2.w;
                acc[12]+=av*b3.x; acc[13]+=av*b3.y; acc[14]+=av*b3.z; acc[15]+=av*b3.w;
            }
            float invf = 1.0f / fac;
#pragma unroll
            for (int j = 0; j < 16; ++j) outr[j] = fmaf(acc[j], invf, outr[j]);
            wsync();
            float4* dp = (float4*)&s1[r * LD2 + cb];
            dp[0] = make_float4(acc[0],  acc[1],  acc[2],  acc[3]);
            dp[1] = make_float4(acc[4],  acc[5],  acc[6],  acc[7]);
            dp[2] = make_float4(acc[8],  acc[9],  acc[10], acc[11]);
            dp[3] = make_float4(acc[12], acc[13], acc[14], acc[15]);
            wsync();
        }
        // E -> s0; Gs_old -> s1
        {
            float4* dp = (float4*)&s0[r * LD2 + cb];
            dp[0] = make_float4(outr[0],  outr[1],  outr[2],  outr[3]);
            dp[1] = make_float4(outr[4],  outr[5],  outr[6],  outr[7]);
            dp[2] = make_float4(outr[8],  outr[9],  outr[10], outr[11]);
            dp[3] = make_float4(outr[12], outr[13], outr[14], outr[15]);
            const float4* Gsb = (const float4*)(Gs + b * 1024);
#pragma unroll
            for (int j4 = 0; j4 < 4; ++j4) {
                float4 v = Gsb[lane * 4 + j4];
                int e = lane * 16 + j4 * 4;
                *((float4*)&s1[(e >> 5) * LD2 + (e & 31)]) = v;
            }
        }
        wsync();
        mm32w(s1, s0, s2, lane);   // T = Gs * E
        mm32w(s2, s1, s0, lane);   // M = T * Gs

        // enforce_spd eigh: cold (symmetrized cols) or warm (M * Vg + JIT Vg)
        float a[16];
        if (Vg == nullptr) {
#pragma unroll
            for (int i = 0; i < 16; ++i) {
                int row = 16 * h + i;
                float own = s0[c * LD2 + row];
                float v = 0.5f * (s0[row * LD2 + c] + own);
                if (row == c) v = own + JIT;
                a[i] = v;
            }
        } else {
            float v[32];
            {
                const float4* Vp = (const float4*)(Vg + b * 1024 + c * 32);
#pragma unroll
                for (int j4 = 0; j4 < 8; ++j4) {
                    float4 t = Vp[j4];
                    v[4*j4] = t.x; v[4*j4+1] = t.y; v[4*j4+2] = t.z; v[4*j4+3] = t.w;
                }
            }
#pragma unroll
            for (int i = 0; i < 16; ++i) {
                const float4* Mr = (const float4*)&s0[(16 * h + i) * LD2];
                float s = 0.f;
#pragma unroll
                for (int j4 = 0; j4 < 8; ++j4) {
                    float4 q = Mr[j4];
                    s = fmaf(q.x, v[4*j4],   s);
                    s = fmaf(q.y, v[4*j4+1], s);
                    s = fmaf(q.z, v[4*j4+2], s);
                    s = fmaf(q.w, v[4*j4+3], s);
                }
                a[i] = fmaf(JIT, v[16 * h + i], s);
            }
        }
        jac1(a, c, hi16, 10, 1e-12f);
        float gs2 = 0.f;
#pragma unroll
        for (int i = 0; i < 16; ++i) gs2 = fmaf(a[i], a[i], gs2);
        gs2 = xhsum(gs2);
        float l = __builtin_amdgcn_sqrtf(gs2);
        float clipl = fmaxf(l, JIT);
        float ig = __builtin_amdgcn_rcpf(gs2);
        float tg = clipl * ig;                      // G:   clip(lam)/lam^2
        float sh = clipl + JIT;                     // next eigh's vals (same eigvecs)
        float ts = __builtin_amdgcn_sqrtf(sh) * ig; // Gs:  sqrt(clip+JIT)/lam^2
        float ti = __builtin_amdgcn_rsqf(sh) * ig;  // Gis: rsqrt(clip+JIT)/lam^2
        if (Vg) {   // store normalized eigvecs for next iteration's warm start
            float inl = __builtin_amdgcn_rsqf(gs2);
            float4* Vp = (float4*)(Vg + b * 1024 + c * 32 + 16 * h);
            Vp[0] = make_float4(a[0]*inl,  a[1]*inl,  a[2]*inl,  a[3]*inl);
            Vp[1] = make_float4(a[4]*inl,  a[5]*inl,  a[6]*inl,  a[7]*inl);
            Vp[2] = make_float4(a[8]*inl,  a[9]*inl,  a[10]*inl, a[11]*inl);
            Vp[3] = make_float4(a[12]*inl, a[13]*inl, a[14]*inl, a[15]*inl);
        }
        wsync();
        // W -> s1, coeffs -> scof
        {
            float4* wp = (float4*)&s1[c * LD2 + 16 * h];
            wp[0] = make_float4(a[0],  a[1],  a[2],  a[3]);
            wp[1] = make_float4(a[4],  a[5],  a[6],  a[7]);
            wp[2] = make_float4(a[8],  a[9],  a[10], a[11]);
            wp[3] = make_float4(a[12], a[13], a[14], a[15]);
            if (h == 0) { scof[c] = tg; scof[32 + c] = ts; scof[64 + c] = ti; }
        }
        wsync();
        // three low-register passes: G, Gs, Gis = W diag(coef) W^T
#pragma unroll 1
        for (int pass = 0; pass < 3; ++pass) {
            float g[16];
#pragma unroll
            for (int j = 0; j < 16; ++j) g[j] = 0.f;
            for (int k = 0; k < DD; ++k) {
                float t1 = s1[k * LD2 + r] * scof[pass * 32 + k];
                const float4* Wc = (const float4*)&s1[k * LD2 + cb];
                float4 w0 = Wc[0], w1 = Wc[1], w2 = Wc[2], w3 = Wc[3];
                g[0]+=t1*w0.x; g[1]+=t1*w0.y; g[2]+=t1*w0.z; g[3]+=t1*w0.w;
                g[4]+=t1*w1.x; g[5]+=t1*w1.y; g[6]+=t1*w1.z; g[7]+=t1*w1.w;
                g[8]+=t1*w2.x; g[9]+=t1*w2.y; g[10]+=t1*w2.z; g[11]+=t1*w2.w;
                g[12]+=t1*w3.x; g[13]+=t1*w3.y; g[14]+=t1*w3.z; g[15]+=t1*w3.w;
            }
            float* dst = (pass == 0) ? G : (pass == 1) ? Gs : Gis;
            float4* Db = (float4*)(dst + b * 1024 + lane * 16);
#pragma unroll
            for (int j4 = 0; j4 < 4; ++j4)
                Db[j4] = make_float4(g[4*j4], g[4*j4+1], g[4*j4+2], g[4*j4+3]);
        }

        // global convergence check by last-finishing batch
        __threadfence();
        if (lane == 0) {
            int r2 = atomicAdd(cnt_all, 1);
            if (r2 == BB - 1) {
                float nm = atomicAdd(norm_acc, 0.f);
                if (nm * (1.0f / BB) < TOLF) *done = 1;
                *norm_acc = 0.f;
                *cnt_all = 0;
                __threadfence();
            }
        }
    }
}

__global__ __launch_bounds__(256) void k5_out(const float* __restrict__ G, float* __restrict__ out) {
    int i = blockIdx.x * 256 + threadIdx.x;
    out[i] = G[i];
}

extern "C" void kernel_launch(void* const* d_in, const int* in_sizes, int n_in,
                              void* d_out, int out_size, void* d_ws, size_t ws_size,
                              hipStream_t stream) {
    const float* X = (const float*)d_in[0];
    float* ws = (float*)d_ws;
    float* G     = ws;                        // 65536
    float* Gs    = ws + 65536;                // 65536
    float* Gis   = ws + 2 * 65536;            // 65536
    float* Part  = ws + 3 * 65536;            // 1024 blocks * 1024 = 1048576
    float* norm_acc = ws + 3 * 65536 + 1048576;
    int*   cnt_all  = (int*)(norm_acc + 1);
    int*   done     = (int*)(norm_acc + 2);
    int*   cnt_b    = (int*)(norm_acc + 3);   // 64 ints
    size_t base_floats = (size_t)3 * 65536 + 1048576 + 80;  // aligned past counters
    // Vg: 64*1024 floats (256 KB) epilogue warm start; Vbuf: 64*512*1024 floats (128 MB) k2 warm start
    float* Vg   = (ws_size >= (base_floats + (size_t)BB * 1024) * sizeof(float))
                  ? (ws + base_floats) : nullptr;
    float* Vbuf = (ws_size >= (base_floats + (size_t)BB * 1024 + (size_t)BB * NN * 1024) * sizeof(float))
                  ? (ws + base_floats + (size_t)BB * 1024) : nullptr;

    k0_zero<<<64, 256, 0, stream>>>(G, done, norm_acc, cnt_all, cnt_b);
    k0_mean<<<512, 256, 0, stream>>>(X, G);
    k1_init<<<64, 64, 0, stream>>>(G, Gs, Gis, Vg);
    for (int it = 0; it < MAXIT; ++it) {
        int it_eff = (Vbuf != nullptr) ? it : 0;
        k2_log_acc<<<1024, 512, 0, stream>>>(X, G, Gs, Gis, Part, done, Vbuf, Vg,
                                             norm_acc, cnt_all, cnt_b, it_eff);
    }
    k5_out<<<256, 256, 0, stream>>>(G, (float*)d_out);
}